// Round 3
// baseline (477.294 us; speedup 1.0000x reference)
//
#include <hip/hip_runtime.h>

#define KNN 16
#define FSEM 32
#define LPG 4                 // 4 lanes cooperate per gaussian
#define NXCD 8
#define NSUB 256              // coarse sub-buckets per time slice

__device__ __forceinline__ float sigmoidf_(float x) { return 1.0f / (1.0f + __expf(-x)); }

// q / clip(|q|,1e-12) -> row-major 3x3
__device__ __forceinline__ void quat_to_R(float qw, float qx, float qy, float qz, float* R) {
    float d = qw * qw + qx * qx + qy * qy + qz * qz;
    float inv = rsqrtf(fmaxf(d, 1e-24f));
    float w = qw * inv, x = qx * inv, y = qy * inv, z = qz * inv;
    R[0] = 1.f - 2.f * (y * y + z * z); R[1] = 2.f * (x * y - w * z); R[2] = 2.f * (x * z + w * y);
    R[3] = 2.f * (x * y + w * z); R[4] = 1.f - 2.f * (x * x + z * z); R[5] = 2.f * (y * z - w * x);
    R[6] = 2.f * (x * z - w * y); R[7] = 2.f * (y * z + w * x); R[8] = 1.f - 2.f * (x * x + y * y);
}

// ---- fused prepack + histogram.
// pack:  packed[p] = {x,y,z,sigma, qw,qx,qy,qz} (32 B, line-friendly)
// hist:  coarse key = rt*NSUB + (a>>shift); rank[n] = arrival order in bucket.
// cnt must be zeroed (hipMemsetAsync) before this kernel. ----
__global__ void __launch_bounds__(256)
k_pack_hist(const float* __restrict__ node_xyz, const float* __restrict__ node_quat,
            const float* __restrict__ node_sigma,
            const int* __restrict__ attach, const int* __restrict__ rtime,
            float* __restrict__ packed, int* __restrict__ cnt, int* __restrict__ rank,
            int TM, int M, int N, int shift)
{
    int p = blockIdx.x * blockDim.x + threadIdx.x;
    if (p < TM) {
        const int node = p - (p / M) * M;          // p % M
        const float* x = node_xyz + 3 * (size_t)p;
        float4 a = make_float4(x[0], x[1], x[2], node_sigma[node]);
        float4 q = reinterpret_cast<const float4*>(node_quat)[p];
        float4* dst = reinterpret_cast<float4*>(packed + 8 * (size_t)p);
        dst[0] = a;
        dst[1] = q;
    }
    if (p < N && cnt) {
        const int key = rtime[p] * NSUB + (attach[p] >> shift);
        rank[p] = atomicAdd(&cnt[key], 1);
    }
}

// single-block exclusive scan over B buckets (B ~ 10K: trivial)
__global__ void __launch_bounds__(256)
k_scan(int* __restrict__ cnt, int B)
{
    __shared__ int sh[256];
    __shared__ int carry_s;
    if (threadIdx.x == 0) carry_s = 0;
    __syncthreads();
    for (int base = 0; base < B; base += 256) {
        const int i = base + threadIdx.x;
        int v = (i < B) ? cnt[i] : 0;
        sh[threadIdx.x] = v;
        __syncthreads();
        int acc = v;
#pragma unroll
        for (int off = 1; off < 256; off <<= 1) {
            int u = (threadIdx.x >= off) ? sh[threadIdx.x - off] : 0;
            __syncthreads();
            acc += u;
            sh[threadIdx.x] = acc;
            __syncthreads();
        }
        const int carry = carry_s;
        if (i < B) cnt[i] = acc - v + carry;
        __syncthreads();
        if (threadIdx.x == 255) carry_s = carry + acc;
        __syncthreads();
    }
}

// meta[2*pos]   = {n, a, rt, 0} (as float bits)
// meta[2*pos+1] = {gx, gy, gz, 0}
__global__ void __launch_bounds__(256)
k_scatter(const int* __restrict__ attach, const int* __restrict__ rtime,
          const float* __restrict__ gs_xyz,
          const int* __restrict__ rank, const int* __restrict__ cnt,
          float4* __restrict__ meta, int N, int shift)
{
    int n = blockIdx.x * blockDim.x + threadIdx.x;
    if (n >= N) return;
    const int a = attach[n], rt = rtime[n];
    const int key = rt * NSUB + (a >> shift);
    const int pos = cnt[key] + rank[n];
    meta[2 * (size_t)pos]     = make_float4(__int_as_float(n), __int_as_float(a),
                                            __int_as_float(rt), 0.f);
    meta[2 * (size_t)pos + 1] = make_float4(gs_xyz[3 * (size_t)n + 0],
                                            gs_xyz[3 * (size_t)n + 1],
                                            gs_xyz[3 * (size_t)n + 2], 0.f);
}

// ---- elementwise outputs + (optionally) the fr_live epilogue ----
template<bool FR>
__global__ void __launch_bounds__(256)
k_elem(const float* __restrict__ gs_scal,
       const float* __restrict__ gs_opa,
       const float* __restrict__ feat_dc,
       const float* __restrict__ feat_rest,
       const float* __restrict__ gs_rot,
       const float* __restrict__ node_quat,
       const int*   __restrict__ attach_ind,
       const int*   __restrict__ ref_time,
       const float* __restrict__ qb_ws,
       float* __restrict__ out, int N, int M)
{
    const int n = blockIdx.x * blockDim.x + threadIdx.x;
    if (n >= N) return;
    const size_t Ns = (size_t)N, ns = (size_t)n;

    float* os = out + 12 * Ns + 3 * ns;
    os[0] = 0.1f * sigmoidf_(gs_scal[3 * ns + 0]);
    os[1] = 0.1f * sigmoidf_(gs_scal[3 * ns + 1]);
    os[2] = 0.1f * sigmoidf_(gs_scal[3 * ns + 2]);

    out[15 * Ns + ns] = sigmoidf_(gs_opa[ns]);

    float* osph = out + 16 * Ns + 12 * ns;   // 16B-aligned
    float4 v0 = make_float4(feat_dc[3 * ns + 0], feat_dc[3 * ns + 1], feat_dc[3 * ns + 2],
                            feat_rest[9 * ns + 0]);
    float4 v1 = make_float4(feat_rest[9 * ns + 1], feat_rest[9 * ns + 2],
                            feat_rest[9 * ns + 3], feat_rest[9 * ns + 4]);
    float4 v2 = make_float4(feat_rest[9 * ns + 5], feat_rest[9 * ns + 6],
                            feat_rest[9 * ns + 7], feat_rest[9 * ns + 8]);
    reinterpret_cast<float4*>(osph)[0] = v0;
    reinterpret_cast<float4*>(osph)[1] = v1;
    reinterpret_cast<float4*>(osph)[2] = v2;

    if constexpr (FR) {
        // fr_live = q2R(qb) @ (Rref @ q2R(gs_rot)); qb already scaled by invw
        // in the main kernel (fp32 subnormal guard).
        const int a  = attach_ind[n];
        const int rt = ref_time[n];
        const float4 qa = reinterpret_cast<const float4*>(node_quat)[(size_t)rt * (size_t)M + (size_t)a];
        float Rref[9];
        quat_to_R(qa.x, qa.y, qa.z, qa.w, Rref);

        const float4 qg = reinterpret_cast<const float4*>(gs_rot)[ns];
        float Rg[9];
        quat_to_R(qg.x, qg.y, qg.z, qg.w, Rg);

        float Rw[9];
#pragma unroll
        for (int i = 0; i < 3; i++)
#pragma unroll
            for (int j = 0; j < 3; j++)
                Rw[3 * i + j] = Rref[3 * i] * Rg[j] + Rref[3 * i + 1] * Rg[3 + j] + Rref[3 * i + 2] * Rg[6 + j];

        const float4 qb = reinterpret_cast<const float4*>(qb_ws)[ns];
        float Rb[9];
        quat_to_R(qb.x, qb.y, qb.z, qb.w, Rb);

        float* ofr = out + 3 * Ns + 9 * ns;
#pragma unroll
        for (int i = 0; i < 3; i++)
#pragma unroll
            for (int j = 0; j < 3; j++)
                ofr[3 * i + j] = Rb[3 * i] * Rw[j] + Rb[3 * i + 1] * Rw[3 + j] + Rb[3 * i + 2] * Rw[6 + j];
    }
}

// ---- main skinning kernel ----
// __launch_bounds__(256, 8): request 8 waves/SIMD -> allocator targets <=64 VGPR
// (88 VGPR sat in the 4-wave band; kernel is gather-latency-bound, needs TLP).
template<bool PACKED, bool FRSPLIT, bool SORTED>
__global__ void __launch_bounds__(256, 8)
dynscf_kernel(const float* __restrict__ gs_xyz,
              const float* __restrict__ gs_rot,
              const float* __restrict__ node_xyz,
              const float* __restrict__ node_quat,
              const float* __restrict__ packed,
              const float* __restrict__ node_sigma,
              const float* __restrict__ node_sem,
              const int* __restrict__ attach_ind,
              const int* __restrict__ ref_time,
              const int* __restrict__ topo_knn,
              const int* __restrict__ t_ptr,
              const float4* __restrict__ meta,
              float* __restrict__ out,
              float* __restrict__ qb_out,
              int N, int M)
{
    int bid = blockIdx.x;
    if (SORTED) {
        // m204 bijective chunked XCD swizzle: each XCD gets a contiguous
        // range of the rt-sorted gaussians -> its L2 holds few rt slices.
        const int nwg = gridDim.x;
        const int q = nwg / NXCD, r = nwg % NXCD;
        const int xcd = bid % NXCD, idx = bid / NXCD;
        bid = (xcd < r ? xcd * (q + 1) : r * (q + 1) + (xcd - r) * q) + idx;
    }
    const int tid = bid * blockDim.x + threadIdx.x;
    const int g   = tid >> 2;            // sorted-order group index
    const int sub = tid & (LPG - 1);
    if (g >= N) return;

    const int t = t_ptr[0];

    int n, a, rt;
    float gx, gy, gz;
    if (SORTED) {
        const float4 m0 = meta[2 * (size_t)g];
        const float4 m1 = meta[2 * (size_t)g + 1];
        n  = __float_as_int(m0.x);
        a  = __float_as_int(m0.y);
        rt = __float_as_int(m0.z);
        gx = m1.x; gy = m1.y; gz = m1.z;
    } else {
        n  = g;
        a  = attach_ind[n];
        rt = ref_time[n];
        gx = gs_xyz[3 * (size_t)n + 0];
        gy = gs_xyz[3 * (size_t)n + 1];
        gz = gs_xyz[3 * (size_t)n + 2];
    }

    const size_t base_rt = (size_t)rt * (size_t)M;
    const size_t base_t  = (size_t)t  * (size_t)M;

    // neighbor indices first so downstream gather addresses are known early
    const int4 kv = reinterpret_cast<const int4*>(topo_knn)[(size_t)a * (KNN / 4) + sub];
    const int js[4] = { kv.x, kv.y, kv.z, kv.w };

    // --- attach node @ ref time ---
    float apx, apy, apz, aqw, aqx, aqy, aqz;
    if (PACKED) {
        const float4* pk = reinterpret_cast<const float4*>(packed + (base_rt + (size_t)a) * 8);
        float4 xz = pk[0], qv = pk[1];
        apx = xz.x; apy = xz.y; apz = xz.z;
        aqw = qv.x; aqx = qv.y; aqy = qv.z; aqz = qv.w;
    } else {
        const float4 qv = *reinterpret_cast<const float4*>(node_quat + (base_rt + (size_t)a) * 4);
        const float* pa = node_xyz + (base_rt + (size_t)a) * 3;
        apx = pa[0]; apy = pa[1]; apz = pa[2];
        aqw = qv.x; aqx = qv.y; aqy = qv.z; aqz = qv.w;
    }
    float Rref[9];
    quat_to_R(aqw, aqx, aqy, aqz, Rref);

    const float xw0 = Rref[0] * gx + Rref[1] * gy + Rref[2] * gz + apx;
    const float xw1 = Rref[3] * gx + Rref[4] * gy + Rref[5] * gz + apy;
    const float xw2 = Rref[6] * gx + Rref[7] * gy + Rref[8] * gz + apz;
    // NOTE: in FRSPLIT mode Rref is dead from here on (k_elem recomputes it).

    float wsum = 0.f, mu0 = 0.f, mu1 = 0.f, mu2 = 0.f;
    float qb0 = 0.f, qb1 = 0.f, qb2 = 0.f, qb3 = 0.f;
    float wk[4];

#pragma unroll
    for (int k = 0; k < KNN / LPG; k++) {
        const int j = js[k];

        float prx, pry, prz, rw, rx, ry, rz;
        float plx, ply, plz, lw, lx, ly, lz;
        float sg;
        if (PACKED) {
            const float4* pkr = reinterpret_cast<const float4*>(packed + (base_rt + (size_t)j) * 8);
            float4 xr = pkr[0], qr = pkr[1];
            prx = xr.x; pry = xr.y; prz = xr.z; sg = xr.w;
            rw = qr.x; rx = qr.y; ry = qr.z; rz = qr.w;
            const float4* pkl = reinterpret_cast<const float4*>(packed + (base_t + (size_t)j) * 8);
            float4 xl = pkl[0], ql = pkl[1];
            plx = xl.x; ply = xl.y; plz = xl.z;
            lw = ql.x; lx = ql.y; ly = ql.z; lz = ql.w;
        } else {
            const float* pr = node_xyz + (base_rt + (size_t)j) * 3;
            prx = pr[0]; pry = pr[1]; prz = pr[2];
            const float4 qr = *reinterpret_cast<const float4*>(node_quat + (base_rt + (size_t)j) * 4);
            rw = qr.x; rx = qr.y; ry = qr.z; rz = qr.w;
            const float* pl = node_xyz + (base_t + (size_t)j) * 3;
            plx = pl[0]; ply = pl[1]; plz = pl[2];
            const float4 ql = *reinterpret_cast<const float4*>(node_quat + (base_t + (size_t)j) * 4);
            lw = ql.x; lx = ql.y; ly = ql.z; lz = ql.w;
            sg = node_sigma[j];
        }

        const float dx = xw0 - prx;
        const float dy = xw1 - pry;
        const float dz = xw2 - prz;
        const float dsq = dx * dx + dy * dy + dz * dz;

        const float w = __expf(-dsq / (2.f * sg * sg + 1e-8f));
        wk[k] = w;

        {
            float inv = rsqrtf(fmaxf(rw * rw + rx * rx + ry * ry + rz * rz, 1e-24f));
            rw *= inv; rx *= inv; ry *= inv; rz *= inv;
        }
        {
            float inv = rsqrtf(fmaxf(lw * lw + lx * lx + ly * ly + lz * lz, 1e-24f));
            lw *= inv; lx *= inv; ly *= inv; lz *= inv;
        }
        // q_rel = q_live * conj(q_ref)
        const float qw =  lw * rw + lx * rx + ly * ry + lz * rz;
        const float qx = -lw * rx + lx * rw - ly * rz + lz * ry;
        const float qy = -lw * ry + lx * rz + ly * rw - lz * rx;
        const float qz = -lw * rz - lx * ry + ly * rx + lz * rw;

        float Rr[9];
        quat_to_R(qw, qx, qy, qz, Rr);

        const float m0 = Rr[0] * dx + Rr[1] * dy + Rr[2] * dz + plx;
        const float m1 = Rr[3] * dx + Rr[4] * dy + Rr[5] * dz + ply;
        const float m2 = Rr[6] * dx + Rr[7] * dy + Rr[8] * dz + plz;

        wsum += w;
        mu0 += w * m0; mu1 += w * m1; mu2 += w * m2;
        qb0 += w * qw; qb1 += w * qx; qb2 += w * qy; qb3 += w * qz;
    }

    // group-reduce the 8 scalar accumulators (2 rounds within the 4-lane group)
#pragma unroll
    for (int m = 1; m < LPG; m <<= 1) {
        wsum += __shfl_xor(wsum, m);
        mu0  += __shfl_xor(mu0, m);  mu1 += __shfl_xor(mu1, m);  mu2 += __shfl_xor(mu2, m);
        qb0  += __shfl_xor(qb0, m);  qb1 += __shfl_xor(qb1, m);
        qb2  += __shfl_xor(qb2, m);  qb3 += __shfl_xor(qb3, m);
    }

    const float invw = 1.f / (wsum + 1e-8f);
    const size_t Ns = (size_t)N, ns = (size_t)n;

    // --- sem: feature-sliced. Lane `sub` owns features [8*sub, 8*sub+8) and
    // walks all 16 neighbors, pulling (j, w) from the owning lane via shfl. ---
    float sm0 = 0.f, sm1 = 0.f, sm2 = 0.f, sm3 = 0.f;
    float sm4 = 0.f, sm5 = 0.f, sm6 = 0.f, sm7 = 0.f;
    const float4* sem4 = reinterpret_cast<const float4*>(node_sem);
#pragma unroll
    for (int kk = 0; kk < KNN; kk++) {
        const int src = kk >> 2;        // lane within group that owns this neighbor
        const int idx = kk & 3;         // compile-time (loop fully unrolled)
        const int   jk = __shfl(js[idx], src, LPG);
        const float wkk = __shfl(wk[idx], src, LPG);
        const float4 v0 = sem4[(size_t)jk * (FSEM / 4) + sub * 2 + 0];
        const float4 v1 = sem4[(size_t)jk * (FSEM / 4) + sub * 2 + 1];
        sm0 += wkk * v0.x; sm1 += wkk * v0.y; sm2 += wkk * v0.z; sm3 += wkk * v0.w;
        sm4 += wkk * v1.x; sm5 += wkk * v1.y; sm6 += wkk * v1.z; sm7 += wkk * v1.w;
    }

    if (sub == 0) {
        out[3 * ns + 0] = mu0 * invw;
        out[3 * ns + 1] = mu1 * invw;
        out[3 * ns + 2] = mu2 * invw;
    } else if (sub == 1) {
        if (FRSPLIT) {
            reinterpret_cast<float4*>(qb_out)[ns] =
                make_float4(qb0 * invw, qb1 * invw, qb2 * invw, qb3 * invw);
        }
    }

    if constexpr (!FRSPLIT) {
        if (sub == 1) {
            // fr_live = q2R(qb*invw) @ (Rref @ q2R(gs_rot)); invw BEFORE q2R (fp32
            // subnormal guard — r5 bug).
            const float4 qg = *reinterpret_cast<const float4*>(gs_rot + 4 * ns);
            float Rg[9];
            quat_to_R(qg.x, qg.y, qg.z, qg.w, Rg);
            float Rw[9];
#pragma unroll
            for (int i = 0; i < 3; i++)
#pragma unroll
                for (int j = 0; j < 3; j++)
                    Rw[3 * i + j] = Rref[3 * i] * Rg[j] + Rref[3 * i + 1] * Rg[3 + j] + Rref[3 * i + 2] * Rg[6 + j];
            float Rb[9];
            quat_to_R(qb0 * invw, qb1 * invw, qb2 * invw, qb3 * invw, Rb);
            float* ofr = out + 3 * Ns + 9 * ns;
#pragma unroll
            for (int i = 0; i < 3; i++)
#pragma unroll
                for (int j = 0; j < 3; j++)
                    ofr[3 * i + j] = Rb[3 * i] * Rw[j] + Rb[3 * i + 1] * Rw[3 + j] + Rb[3 * i + 2] * Rw[6 + j];
        }
    }

    // sem_live: [28N, 60N); lane writes its own 2 float4s (one 128 B line/gaussian)
    float4* osem = reinterpret_cast<float4*>(out + 28 * Ns + FSEM * ns);
    osem[sub * 2 + 0] = make_float4(sm0 * invw, sm1 * invw, sm2 * invw, sm3 * invw);
    osem[sub * 2 + 1] = make_float4(sm4 * invw, sm5 * invw, sm6 * invw, sm7 * invw);
}

extern "C" void kernel_launch(void* const* d_in, const int* in_sizes, int n_in,
                              void* d_out, int out_size, void* d_ws, size_t ws_size,
                              hipStream_t stream)
{
    const float* gs_xyz     = (const float*)d_in[0];
    const float* gs_rot     = (const float*)d_in[1];
    const float* gs_scal    = (const float*)d_in[2];
    const float* gs_opa     = (const float*)d_in[3];
    const float* feat_dc    = (const float*)d_in[4];
    const float* feat_rest  = (const float*)d_in[5];
    const float* node_xyz   = (const float*)d_in[6];
    const float* node_quat  = (const float*)d_in[7];
    const float* node_sigma = (const float*)d_in[8];
    const float* node_sem   = (const float*)d_in[9];
    const int* attach_ind   = (const int*)d_in[10];
    const int* ref_time     = (const int*)d_in[11];
    const int* topo_knn     = (const int*)d_in[12];
    const int* t_ptr        = (const int*)d_in[13];

    const int N = in_sizes[0] / 3;
    const int M = in_sizes[8];                 // node_sigma is (M,1)
    const int TM = in_sizes[6] / 3;            // T*M
    const int T  = TM / M;
    const int B  = T * NSUB;                   // coarse buckets: rt x (a>>shift)

    int shift = 0;
    while (((M - 1) >> shift) >= NSUB) shift++;

    float* out = (float*)d_out;

    const int block = 256;
    const int gridN = (N + block - 1) / block;
    const long long threads = (long long)N * LPG;
    const int gridM = (int)((threads + block - 1) / block);
    const int gridPH = (((TM > N ? TM : N)) + block - 1) / block;

    // workspace layout (floats): packed | qb | meta(2*float4/gauss) | cnt
    // rank aliases qb (qb written only by main kernel, after scatter consumed rank)
    const size_t f_packed = (size_t)TM * 8;
    const size_t f_qb     = (size_t)N * 4;
    const size_t f_meta   = (size_t)N * 8;
    const size_t i_cnt    = (size_t)B;
    const size_t need_sort   = (f_packed + f_qb + f_meta + i_cnt) * sizeof(float);
    const size_t need_packed = (f_packed + f_qb) * sizeof(float);
    const size_t need_qb     = f_qb * sizeof(float);

    if (ws_size >= need_sort) {
        float*  packed = (float*)d_ws;
        float*  qb_ws  = packed + f_packed;
        float4* meta   = (float4*)(packed + f_packed + f_qb);
        int*    cnt    = (int*)(packed + f_packed + f_qb + f_meta);
        int*    rank   = (int*)qb_ws;

        hipMemsetAsync(cnt, 0, (size_t)B * sizeof(int), stream);
        hipLaunchKernelGGL(k_pack_hist, dim3(gridPH), dim3(block), 0, stream,
                           node_xyz, node_quat, node_sigma, attach_ind, ref_time,
                           packed, cnt, rank, TM, M, N, shift);
        hipLaunchKernelGGL(k_scan, dim3(1), dim3(block), 0, stream, cnt, B);
        hipLaunchKernelGGL(k_scatter, dim3(gridN), dim3(block), 0, stream,
                           attach_ind, ref_time, gs_xyz, rank, cnt, meta, N, shift);
        hipLaunchKernelGGL((dynscf_kernel<true, true, true>), dim3(gridM), dim3(block), 0, stream,
                           gs_xyz, gs_rot, node_xyz, node_quat, packed, node_sigma, node_sem,
                           attach_ind, ref_time, topo_knn, t_ptr, meta, out, qb_ws, N, M);
        hipLaunchKernelGGL((k_elem<true>), dim3(gridN), dim3(block), 0, stream,
                           gs_scal, gs_opa, feat_dc, feat_rest, gs_rot, node_quat,
                           attach_ind, ref_time, qb_ws, out, N, M);
    } else if (ws_size >= need_packed) {
        float* packed = (float*)d_ws;
        float* qb_ws  = packed + f_packed;
        hipLaunchKernelGGL(k_pack_hist, dim3(gridPH), dim3(block), 0, stream,
                           node_xyz, node_quat, node_sigma, attach_ind, ref_time,
                           packed, (int*)nullptr, (int*)nullptr, TM, M, 0, shift);
        hipLaunchKernelGGL((dynscf_kernel<true, true, false>), dim3(gridM), dim3(block), 0, stream,
                           gs_xyz, gs_rot, node_xyz, node_quat, packed, node_sigma, node_sem,
                           attach_ind, ref_time, topo_knn, t_ptr, (const float4*)nullptr,
                           out, qb_ws, N, M);
        hipLaunchKernelGGL((k_elem<true>), dim3(gridN), dim3(block), 0, stream,
                           gs_scal, gs_opa, feat_dc, feat_rest, gs_rot, node_quat,
                           attach_ind, ref_time, qb_ws, out, N, M);
    } else if (ws_size >= need_qb) {
        float* qb_ws = (float*)d_ws;
        hipLaunchKernelGGL((dynscf_kernel<false, true, false>), dim3(gridM), dim3(block), 0, stream,
                           gs_xyz, gs_rot, node_xyz, node_quat, (const float*)nullptr,
                           node_sigma, node_sem,
                           attach_ind, ref_time, topo_knn, t_ptr, (const float4*)nullptr,
                           out, qb_ws, N, M);
        hipLaunchKernelGGL((k_elem<true>), dim3(gridN), dim3(block), 0, stream,
                           gs_scal, gs_opa, feat_dc, feat_rest, gs_rot, node_quat,
                           attach_ind, ref_time, qb_ws, out, N, M);
    } else {
        hipLaunchKernelGGL((dynscf_kernel<false, false, false>), dim3(gridM), dim3(block), 0, stream,
                           gs_xyz, gs_rot, node_xyz, node_quat, (const float*)nullptr,
                           node_sigma, node_sem,
                           attach_ind, ref_time, topo_knn, t_ptr, (const float4*)nullptr,
                           out, (float*)nullptr, N, M);
        hipLaunchKernelGGL((k_elem<false>), dim3(gridN), dim3(block), 0, stream,
                           gs_scal, gs_opa, feat_dc, feat_rest, gs_rot, node_quat,
                           attach_ind, ref_time, (const float*)nullptr, out, N, M);
    }
}

// Round 4
// 244.230 us; speedup vs baseline: 1.9543x; 1.9543x over previous
//
#include <hip/hip_runtime.h>

#define KNN 16
#define FSEM 32
#define LPG 4                 // 4 lanes cooperate per gaussian
#define NXCD 8
#define NSUB 256              // coarse sub-buckets per time slice

__device__ __forceinline__ float sigmoidf_(float x) { return 1.0f / (1.0f + __expf(-x)); }

// q / clip(|q|,1e-12) -> row-major 3x3
__device__ __forceinline__ void quat_to_R(float qw, float qx, float qy, float qz, float* R) {
    float d = qw * qw + qx * qx + qy * qy + qz * qz;
    float inv = rsqrtf(fmaxf(d, 1e-24f));
    float w = qw * inv, x = qx * inv, y = qy * inv, z = qz * inv;
    R[0] = 1.f - 2.f * (y * y + z * z); R[1] = 2.f * (x * y - w * z); R[2] = 2.f * (x * z + w * y);
    R[3] = 2.f * (x * y + w * z); R[4] = 1.f - 2.f * (x * x + z * z); R[5] = 2.f * (y * z - w * x);
    R[6] = 2.f * (x * z - w * y); R[7] = 2.f * (y * z + w * x); R[8] = 1.f - 2.f * (x * x + y * y);
}

// ---- fused prepack + histogram.
// pack:  packed[p] = {x,y,z,sigma, qw,qx,qy,qz} (32 B, line-friendly)
// hist:  coarse key = rt*NSUB + (a>>shift); rank[n] = arrival order in bucket.
// cnt must be zeroed (hipMemsetAsync) before this kernel. ----
__global__ void __launch_bounds__(256)
k_pack_hist(const float* __restrict__ node_xyz, const float* __restrict__ node_quat,
            const float* __restrict__ node_sigma,
            const int* __restrict__ attach, const int* __restrict__ rtime,
            float* __restrict__ packed, int* __restrict__ cnt, int* __restrict__ rank,
            int TM, int M, int N, int shift)
{
    int p = blockIdx.x * blockDim.x + threadIdx.x;
    if (p < TM) {
        const int node = p - (p / M) * M;          // p % M
        const float* x = node_xyz + 3 * (size_t)p;
        float4 a = make_float4(x[0], x[1], x[2], node_sigma[node]);
        float4 q = reinterpret_cast<const float4*>(node_quat)[p];
        float4* dst = reinterpret_cast<float4*>(packed + 8 * (size_t)p);
        dst[0] = a;
        dst[1] = q;
    }
    if (p < N && cnt) {
        const int key = rtime[p] * NSUB + (attach[p] >> shift);
        rank[p] = atomicAdd(&cnt[key], 1);
    }
}

// single-block exclusive scan over B buckets (B ~ 10K: trivial)
__global__ void __launch_bounds__(256)
k_scan(int* __restrict__ cnt, int B)
{
    __shared__ int sh[256];
    __shared__ int carry_s;
    if (threadIdx.x == 0) carry_s = 0;
    __syncthreads();
    for (int base = 0; base < B; base += 256) {
        const int i = base + threadIdx.x;
        int v = (i < B) ? cnt[i] : 0;
        sh[threadIdx.x] = v;
        __syncthreads();
        int acc = v;
#pragma unroll
        for (int off = 1; off < 256; off <<= 1) {
            int u = (threadIdx.x >= off) ? sh[threadIdx.x - off] : 0;
            __syncthreads();
            acc += u;
            sh[threadIdx.x] = acc;
            __syncthreads();
        }
        const int carry = carry_s;
        if (i < B) cnt[i] = acc - v + carry;
        __syncthreads();
        if (threadIdx.x == 255) carry_s = carry + acc;
        __syncthreads();
    }
}

// ---- scatter + independent elementwise outputs (s, o, sph) fused.
// meta[2*pos]   = {n, a, rt, 0} (as float bits)
// meta[2*pos+1] = {gx, gy, gz, 0}
// s/o/sph depend on nothing else -> free overlap with the sort chain's stores.
__global__ void __launch_bounds__(256)
k_scatter_elem(const int* __restrict__ attach, const int* __restrict__ rtime,
               const float* __restrict__ gs_xyz,
               const int* __restrict__ rank, const int* __restrict__ cnt,
               float4* __restrict__ meta,
               const float* __restrict__ gs_scal,
               const float* __restrict__ gs_opa,
               const float* __restrict__ feat_dc,
               const float* __restrict__ feat_rest,
               float* __restrict__ out,
               int N, int shift)
{
    int n = blockIdx.x * blockDim.x + threadIdx.x;
    if (n >= N) return;
    const int a = attach[n], rt = rtime[n];
    const int key = rt * NSUB + (a >> shift);
    const int pos = cnt[key] + rank[n];
    meta[2 * (size_t)pos]     = make_float4(__int_as_float(n), __int_as_float(a),
                                            __int_as_float(rt), 0.f);
    meta[2 * (size_t)pos + 1] = make_float4(gs_xyz[3 * (size_t)n + 0],
                                            gs_xyz[3 * (size_t)n + 1],
                                            gs_xyz[3 * (size_t)n + 2], 0.f);

    const size_t Ns = (size_t)N, ns = (size_t)n;
    float* os = out + 12 * Ns + 3 * ns;
    os[0] = 0.1f * sigmoidf_(gs_scal[3 * ns + 0]);
    os[1] = 0.1f * sigmoidf_(gs_scal[3 * ns + 1]);
    os[2] = 0.1f * sigmoidf_(gs_scal[3 * ns + 2]);

    out[15 * Ns + ns] = sigmoidf_(gs_opa[ns]);

    float* osph = out + 16 * Ns + 12 * ns;   // 16B-aligned
    float4 v0 = make_float4(feat_dc[3 * ns + 0], feat_dc[3 * ns + 1], feat_dc[3 * ns + 2],
                            feat_rest[9 * ns + 0]);
    float4 v1 = make_float4(feat_rest[9 * ns + 1], feat_rest[9 * ns + 2],
                            feat_rest[9 * ns + 3], feat_rest[9 * ns + 4]);
    float4 v2 = make_float4(feat_rest[9 * ns + 5], feat_rest[9 * ns + 6],
                            feat_rest[9 * ns + 7], feat_rest[9 * ns + 8]);
    reinterpret_cast<float4*>(osph)[0] = v0;
    reinterpret_cast<float4*>(osph)[1] = v1;
    reinterpret_cast<float4*>(osph)[2] = v2;
}

// ---- fr_live-only epilogue (runs after main; reads qb from workspace) ----
__global__ void __launch_bounds__(256)
k_fr(const float* __restrict__ gs_rot,
     const float* __restrict__ node_quat,
     const int*   __restrict__ attach_ind,
     const int*   __restrict__ ref_time,
     const float* __restrict__ qb_ws,
     float* __restrict__ out, int N, int M)
{
    const int n = blockIdx.x * blockDim.x + threadIdx.x;
    if (n >= N) return;
    const size_t Ns = (size_t)N, ns = (size_t)n;

    // fr_live = q2R(qb) @ (Rref @ q2R(gs_rot)); qb already scaled by invw
    // in the main kernel (fp32 subnormal guard).
    const int a  = attach_ind[n];
    const int rt = ref_time[n];
    const float4 qa = reinterpret_cast<const float4*>(node_quat)[(size_t)rt * (size_t)M + (size_t)a];
    float Rref[9];
    quat_to_R(qa.x, qa.y, qa.z, qa.w, Rref);

    const float4 qg = reinterpret_cast<const float4*>(gs_rot)[ns];
    float Rg[9];
    quat_to_R(qg.x, qg.y, qg.z, qg.w, Rg);

    float Rw[9];
#pragma unroll
    for (int i = 0; i < 3; i++)
#pragma unroll
        for (int j = 0; j < 3; j++)
            Rw[3 * i + j] = Rref[3 * i] * Rg[j] + Rref[3 * i + 1] * Rg[3 + j] + Rref[3 * i + 2] * Rg[6 + j];

    const float4 qb = reinterpret_cast<const float4*>(qb_ws)[ns];
    float Rb[9];
    quat_to_R(qb.x, qb.y, qb.z, qb.w, Rb);

    float* ofr = out + 3 * Ns + 9 * ns;
#pragma unroll
    for (int i = 0; i < 3; i++)
#pragma unroll
        for (int j = 0; j < 3; j++)
            ofr[3 * i + j] = Rb[3 * i] * Rw[j] + Rb[3 * i + 1] * Rw[3 + j] + Rb[3 * i + 2] * Rw[6 + j];
}

// ---- full elementwise kernel (fallback paths only) ----
template<bool FR>
__global__ void __launch_bounds__(256)
k_elem(const float* __restrict__ gs_scal,
       const float* __restrict__ gs_opa,
       const float* __restrict__ feat_dc,
       const float* __restrict__ feat_rest,
       const float* __restrict__ gs_rot,
       const float* __restrict__ node_quat,
       const int*   __restrict__ attach_ind,
       const int*   __restrict__ ref_time,
       const float* __restrict__ qb_ws,
       float* __restrict__ out, int N, int M)
{
    const int n = blockIdx.x * blockDim.x + threadIdx.x;
    if (n >= N) return;
    const size_t Ns = (size_t)N, ns = (size_t)n;

    float* os = out + 12 * Ns + 3 * ns;
    os[0] = 0.1f * sigmoidf_(gs_scal[3 * ns + 0]);
    os[1] = 0.1f * sigmoidf_(gs_scal[3 * ns + 1]);
    os[2] = 0.1f * sigmoidf_(gs_scal[3 * ns + 2]);

    out[15 * Ns + ns] = sigmoidf_(gs_opa[ns]);

    float* osph = out + 16 * Ns + 12 * ns;
    float4 v0 = make_float4(feat_dc[3 * ns + 0], feat_dc[3 * ns + 1], feat_dc[3 * ns + 2],
                            feat_rest[9 * ns + 0]);
    float4 v1 = make_float4(feat_rest[9 * ns + 1], feat_rest[9 * ns + 2],
                            feat_rest[9 * ns + 3], feat_rest[9 * ns + 4]);
    float4 v2 = make_float4(feat_rest[9 * ns + 5], feat_rest[9 * ns + 6],
                            feat_rest[9 * ns + 7], feat_rest[9 * ns + 8]);
    reinterpret_cast<float4*>(osph)[0] = v0;
    reinterpret_cast<float4*>(osph)[1] = v1;
    reinterpret_cast<float4*>(osph)[2] = v2;

    if constexpr (FR) {
        const int a  = attach_ind[n];
        const int rt = ref_time[n];
        const float4 qa = reinterpret_cast<const float4*>(node_quat)[(size_t)rt * (size_t)M + (size_t)a];
        float Rref[9];
        quat_to_R(qa.x, qa.y, qa.z, qa.w, Rref);

        const float4 qg = reinterpret_cast<const float4*>(gs_rot)[ns];
        float Rg[9];
        quat_to_R(qg.x, qg.y, qg.z, qg.w, Rg);

        float Rw[9];
#pragma unroll
        for (int i = 0; i < 3; i++)
#pragma unroll
            for (int j = 0; j < 3; j++)
                Rw[3 * i + j] = Rref[3 * i] * Rg[j] + Rref[3 * i + 1] * Rg[3 + j] + Rref[3 * i + 2] * Rg[6 + j];

        const float4 qb = reinterpret_cast<const float4*>(qb_ws)[ns];
        float Rb[9];
        quat_to_R(qb.x, qb.y, qb.z, qb.w, Rb);

        float* ofr = out + 3 * Ns + 9 * ns;
#pragma unroll
        for (int i = 0; i < 3; i++)
#pragma unroll
            for (int j = 0; j < 3; j++)
                ofr[3 * i + j] = Rb[3 * i] * Rw[j] + Rb[3 * i + 1] * Rw[3 + j] + Rb[3 * i + 2] * Rw[6 + j];
    }
}

// ---- main skinning kernel ----
// Plain __launch_bounds__(256): R3 proved forcing 8 waves/SIMD clamps the
// allocator to 32 VGPR and spills the whole working set (WRITE_SIZE 40->511 MB,
// 67->306 us). Natural allocation is 88 VGPR / ~5 waves per SIMD.
template<bool PACKED, bool FRSPLIT, bool SORTED>
__global__ void __launch_bounds__(256)
dynscf_kernel(const float* __restrict__ gs_xyz,
              const float* __restrict__ gs_rot,
              const float* __restrict__ node_xyz,
              const float* __restrict__ node_quat,
              const float* __restrict__ packed,
              const float* __restrict__ node_sigma,
              const float* __restrict__ node_sem,
              const int* __restrict__ attach_ind,
              const int* __restrict__ ref_time,
              const int* __restrict__ topo_knn,
              const int* __restrict__ t_ptr,
              const float4* __restrict__ meta,
              float* __restrict__ out,
              float* __restrict__ qb_out,
              int N, int M)
{
    int bid = blockIdx.x;
    if (SORTED) {
        // m204 bijective chunked XCD swizzle: each XCD gets a contiguous
        // range of the rt-sorted gaussians -> its L2 holds few rt slices.
        const int nwg = gridDim.x;
        const int q = nwg / NXCD, r = nwg % NXCD;
        const int xcd = bid % NXCD, idx = bid / NXCD;
        bid = (xcd < r ? xcd * (q + 1) : r * (q + 1) + (xcd - r) * q) + idx;
    }
    const int tid = bid * blockDim.x + threadIdx.x;
    const int g   = tid >> 2;            // sorted-order group index
    const int sub = tid & (LPG - 1);
    if (g >= N) return;

    const int t = t_ptr[0];

    int n, a, rt;
    float gx, gy, gz;
    if (SORTED) {
        const float4 m0 = meta[2 * (size_t)g];
        const float4 m1 = meta[2 * (size_t)g + 1];
        n  = __float_as_int(m0.x);
        a  = __float_as_int(m0.y);
        rt = __float_as_int(m0.z);
        gx = m1.x; gy = m1.y; gz = m1.z;
    } else {
        n  = g;
        a  = attach_ind[n];
        rt = ref_time[n];
        gx = gs_xyz[3 * (size_t)n + 0];
        gy = gs_xyz[3 * (size_t)n + 1];
        gz = gs_xyz[3 * (size_t)n + 2];
    }

    const size_t base_rt = (size_t)rt * (size_t)M;
    const size_t base_t  = (size_t)t  * (size_t)M;

    // neighbor indices first so downstream gather addresses are known early
    const int4 kv = reinterpret_cast<const int4*>(topo_knn)[(size_t)a * (KNN / 4) + sub];
    const int js[4] = { kv.x, kv.y, kv.z, kv.w };

    // --- attach node @ ref time ---
    float apx, apy, apz, aqw, aqx, aqy, aqz;
    if (PACKED) {
        const float4* pk = reinterpret_cast<const float4*>(packed + (base_rt + (size_t)a) * 8);
        float4 xz = pk[0], qv = pk[1];
        apx = xz.x; apy = xz.y; apz = xz.z;
        aqw = qv.x; aqx = qv.y; aqy = qv.z; aqz = qv.w;
    } else {
        const float4 qv = *reinterpret_cast<const float4*>(node_quat + (base_rt + (size_t)a) * 4);
        const float* pa = node_xyz + (base_rt + (size_t)a) * 3;
        apx = pa[0]; apy = pa[1]; apz = pa[2];
        aqw = qv.x; aqx = qv.y; aqy = qv.z; aqz = qv.w;
    }
    float Rref[9];
    quat_to_R(aqw, aqx, aqy, aqz, Rref);

    const float xw0 = Rref[0] * gx + Rref[1] * gy + Rref[2] * gz + apx;
    const float xw1 = Rref[3] * gx + Rref[4] * gy + Rref[5] * gz + apy;
    const float xw2 = Rref[6] * gx + Rref[7] * gy + Rref[8] * gz + apz;
    // NOTE: in FRSPLIT mode Rref is dead from here on (k_fr recomputes it).

    float wsum = 0.f, mu0 = 0.f, mu1 = 0.f, mu2 = 0.f;
    float qb0 = 0.f, qb1 = 0.f, qb2 = 0.f, qb3 = 0.f;
    float wk[4];

#pragma unroll
    for (int k = 0; k < KNN / LPG; k++) {
        const int j = js[k];

        float prx, pry, prz, rw, rx, ry, rz;
        float plx, ply, plz, lw, lx, ly, lz;
        float sg;
        if (PACKED) {
            const float4* pkr = reinterpret_cast<const float4*>(packed + (base_rt + (size_t)j) * 8);
            float4 xr = pkr[0], qr = pkr[1];
            prx = xr.x; pry = xr.y; prz = xr.z; sg = xr.w;
            rw = qr.x; rx = qr.y; ry = qr.z; rz = qr.w;
            const float4* pkl = reinterpret_cast<const float4*>(packed + (base_t + (size_t)j) * 8);
            float4 xl = pkl[0], ql = pkl[1];
            plx = xl.x; ply = xl.y; plz = xl.z;
            lw = ql.x; lx = ql.y; ly = ql.z; lz = ql.w;
        } else {
            const float* pr = node_xyz + (base_rt + (size_t)j) * 3;
            prx = pr[0]; pry = pr[1]; prz = pr[2];
            const float4 qr = *reinterpret_cast<const float4*>(node_quat + (base_rt + (size_t)j) * 4);
            rw = qr.x; rx = qr.y; ry = qr.z; rz = qr.w;
            const float* pl = node_xyz + (base_t + (size_t)j) * 3;
            plx = pl[0]; ply = pl[1]; plz = pl[2];
            const float4 ql = *reinterpret_cast<const float4*>(node_quat + (base_t + (size_t)j) * 4);
            lw = ql.x; lx = ql.y; ly = ql.z; lz = ql.w;
            sg = node_sigma[j];
        }

        const float dx = xw0 - prx;
        const float dy = xw1 - pry;
        const float dz = xw2 - prz;
        const float dsq = dx * dx + dy * dy + dz * dz;

        const float w = __expf(-dsq / (2.f * sg * sg + 1e-8f));
        wk[k] = w;

        {
            float inv = rsqrtf(fmaxf(rw * rw + rx * rx + ry * ry + rz * rz, 1e-24f));
            rw *= inv; rx *= inv; ry *= inv; rz *= inv;
        }
        {
            float inv = rsqrtf(fmaxf(lw * lw + lx * lx + ly * ly + lz * lz, 1e-24f));
            lw *= inv; lx *= inv; ly *= inv; lz *= inv;
        }
        // q_rel = q_live * conj(q_ref)
        const float qw =  lw * rw + lx * rx + ly * ry + lz * rz;
        const float qx = -lw * rx + lx * rw - ly * rz + lz * ry;
        const float qy = -lw * ry + lx * rz + ly * rw - lz * rx;
        const float qz = -lw * rz - lx * ry + ly * rx + lz * rw;

        float Rr[9];
        quat_to_R(qw, qx, qy, qz, Rr);

        const float m0 = Rr[0] * dx + Rr[1] * dy + Rr[2] * dz + plx;
        const float m1 = Rr[3] * dx + Rr[4] * dy + Rr[5] * dz + ply;
        const float m2 = Rr[6] * dx + Rr[7] * dy + Rr[8] * dz + plz;

        wsum += w;
        mu0 += w * m0; mu1 += w * m1; mu2 += w * m2;
        qb0 += w * qw; qb1 += w * qx; qb2 += w * qy; qb3 += w * qz;
    }

    // group-reduce the 8 scalar accumulators (2 rounds within the 4-lane group)
#pragma unroll
    for (int m = 1; m < LPG; m <<= 1) {
        wsum += __shfl_xor(wsum, m);
        mu0  += __shfl_xor(mu0, m);  mu1 += __shfl_xor(mu1, m);  mu2 += __shfl_xor(mu2, m);
        qb0  += __shfl_xor(qb0, m);  qb1 += __shfl_xor(qb1, m);
        qb2  += __shfl_xor(qb2, m);  qb3 += __shfl_xor(qb3, m);
    }

    const float invw = 1.f / (wsum + 1e-8f);
    const size_t Ns = (size_t)N, ns = (size_t)n;

    // --- sem: feature-sliced. Lane `sub` owns features [8*sub, 8*sub+8) and
    // walks all 16 neighbors, pulling (j, w) from the owning lane via shfl. ---
    float sm0 = 0.f, sm1 = 0.f, sm2 = 0.f, sm3 = 0.f;
    float sm4 = 0.f, sm5 = 0.f, sm6 = 0.f, sm7 = 0.f;
    const float4* sem4 = reinterpret_cast<const float4*>(node_sem);
#pragma unroll
    for (int kk = 0; kk < KNN; kk++) {
        const int src = kk >> 2;        // lane within group that owns this neighbor
        const int idx = kk & 3;         // compile-time (loop fully unrolled)
        const int   jk = __shfl(js[idx], src, LPG);
        const float wkk = __shfl(wk[idx], src, LPG);
        const float4 v0 = sem4[(size_t)jk * (FSEM / 4) + sub * 2 + 0];
        const float4 v1 = sem4[(size_t)jk * (FSEM / 4) + sub * 2 + 1];
        sm0 += wkk * v0.x; sm1 += wkk * v0.y; sm2 += wkk * v0.z; sm3 += wkk * v0.w;
        sm4 += wkk * v1.x; sm5 += wkk * v1.y; sm6 += wkk * v1.z; sm7 += wkk * v1.w;
    }

    if (sub == 0) {
        out[3 * ns + 0] = mu0 * invw;
        out[3 * ns + 1] = mu1 * invw;
        out[3 * ns + 2] = mu2 * invw;
    } else if (sub == 1) {
        if (FRSPLIT) {
            reinterpret_cast<float4*>(qb_out)[ns] =
                make_float4(qb0 * invw, qb1 * invw, qb2 * invw, qb3 * invw);
        }
    }

    if constexpr (!FRSPLIT) {
        if (sub == 1) {
            // fr_live = q2R(qb*invw) @ (Rref @ q2R(gs_rot)); invw BEFORE q2R (fp32
            // subnormal guard — r5 bug).
            const float4 qg = *reinterpret_cast<const float4*>(gs_rot + 4 * ns);
            float Rg[9];
            quat_to_R(qg.x, qg.y, qg.z, qg.w, Rg);
            float Rw[9];
#pragma unroll
            for (int i = 0; i < 3; i++)
#pragma unroll
                for (int j = 0; j < 3; j++)
                    Rw[3 * i + j] = Rref[3 * i] * Rg[j] + Rref[3 * i + 1] * Rg[3 + j] + Rref[3 * i + 2] * Rg[6 + j];
            float Rb[9];
            quat_to_R(qb0 * invw, qb1 * invw, qb2 * invw, qb3 * invw, Rb);
            float* ofr = out + 3 * Ns + 9 * ns;
#pragma unroll
            for (int i = 0; i < 3; i++)
#pragma unroll
                for (int j = 0; j < 3; j++)
                    ofr[3 * i + j] = Rb[3 * i] * Rw[j] + Rb[3 * i + 1] * Rw[3 + j] + Rb[3 * i + 2] * Rw[6 + j];
        }
    }

    // sem_live: [28N, 60N); lane writes its own 2 float4s (one 128 B line/gaussian)
    float4* osem = reinterpret_cast<float4*>(out + 28 * Ns + FSEM * ns);
    osem[sub * 2 + 0] = make_float4(sm0 * invw, sm1 * invw, sm2 * invw, sm3 * invw);
    osem[sub * 2 + 1] = make_float4(sm4 * invw, sm5 * invw, sm6 * invw, sm7 * invw);
}

extern "C" void kernel_launch(void* const* d_in, const int* in_sizes, int n_in,
                              void* d_out, int out_size, void* d_ws, size_t ws_size,
                              hipStream_t stream)
{
    const float* gs_xyz     = (const float*)d_in[0];
    const float* gs_rot     = (const float*)d_in[1];
    const float* gs_scal    = (const float*)d_in[2];
    const float* gs_opa     = (const float*)d_in[3];
    const float* feat_dc    = (const float*)d_in[4];
    const float* feat_rest  = (const float*)d_in[5];
    const float* node_xyz   = (const float*)d_in[6];
    const float* node_quat  = (const float*)d_in[7];
    const float* node_sigma = (const float*)d_in[8];
    const float* node_sem   = (const float*)d_in[9];
    const int* attach_ind   = (const int*)d_in[10];
    const int* ref_time     = (const int*)d_in[11];
    const int* topo_knn     = (const int*)d_in[12];
    const int* t_ptr        = (const int*)d_in[13];

    const int N = in_sizes[0] / 3;
    const int M = in_sizes[8];                 // node_sigma is (M,1)
    const int TM = in_sizes[6] / 3;            // T*M
    const int T  = TM / M;
    const int B  = T * NSUB;                   // coarse buckets: rt x (a>>shift)

    int shift = 0;
    while (((M - 1) >> shift) >= NSUB) shift++;

    float* out = (float*)d_out;

    const int block = 256;
    const int gridN = (N + block - 1) / block;
    const long long threads = (long long)N * LPG;
    const int gridM = (int)((threads + block - 1) / block);
    const int gridPH = (((TM > N ? TM : N)) + block - 1) / block;

    // workspace layout (floats): packed | qb | meta(2*float4/gauss) | cnt
    // rank aliases qb (qb written only by main kernel, after scatter consumed rank)
    const size_t f_packed = (size_t)TM * 8;
    const size_t f_qb     = (size_t)N * 4;
    const size_t f_meta   = (size_t)N * 8;
    const size_t i_cnt    = (size_t)B;
    const size_t need_sort   = (f_packed + f_qb + f_meta + i_cnt) * sizeof(float);
    const size_t need_packed = (f_packed + f_qb) * sizeof(float);
    const size_t need_qb     = f_qb * sizeof(float);

    if (ws_size >= need_sort) {
        float*  packed = (float*)d_ws;
        float*  qb_ws  = packed + f_packed;
        float4* meta   = (float4*)(packed + f_packed + f_qb);
        int*    cnt    = (int*)(packed + f_packed + f_qb + f_meta);
        int*    rank   = (int*)qb_ws;

        hipMemsetAsync(cnt, 0, (size_t)B * sizeof(int), stream);
        hipLaunchKernelGGL(k_pack_hist, dim3(gridPH), dim3(block), 0, stream,
                           node_xyz, node_quat, node_sigma, attach_ind, ref_time,
                           packed, cnt, rank, TM, M, N, shift);
        hipLaunchKernelGGL(k_scan, dim3(1), dim3(block), 0, stream, cnt, B);
        hipLaunchKernelGGL(k_scatter_elem, dim3(gridN), dim3(block), 0, stream,
                           attach_ind, ref_time, gs_xyz, rank, cnt, meta,
                           gs_scal, gs_opa, feat_dc, feat_rest, out, N, shift);
        hipLaunchKernelGGL((dynscf_kernel<true, true, true>), dim3(gridM), dim3(block), 0, stream,
                           gs_xyz, gs_rot, node_xyz, node_quat, packed, node_sigma, node_sem,
                           attach_ind, ref_time, topo_knn, t_ptr, meta, out, qb_ws, N, M);
        hipLaunchKernelGGL(k_fr, dim3(gridN), dim3(block), 0, stream,
                           gs_rot, node_quat, attach_ind, ref_time, qb_ws, out, N, M);
    } else if (ws_size >= need_packed) {
        float* packed = (float*)d_ws;
        float* qb_ws  = packed + f_packed;
        hipLaunchKernelGGL(k_pack_hist, dim3(gridPH), dim3(block), 0, stream,
                           node_xyz, node_quat, node_sigma, attach_ind, ref_time,
                           packed, (int*)nullptr, (int*)nullptr, TM, M, 0, shift);
        hipLaunchKernelGGL((dynscf_kernel<true, true, false>), dim3(gridM), dim3(block), 0, stream,
                           gs_xyz, gs_rot, node_xyz, node_quat, packed, node_sigma, node_sem,
                           attach_ind, ref_time, topo_knn, t_ptr, (const float4*)nullptr,
                           out, qb_ws, N, M);
        hipLaunchKernelGGL((k_elem<true>), dim3(gridN), dim3(block), 0, stream,
                           gs_scal, gs_opa, feat_dc, feat_rest, gs_rot, node_quat,
                           attach_ind, ref_time, qb_ws, out, N, M);
    } else if (ws_size >= need_qb) {
        float* qb_ws = (float*)d_ws;
        hipLaunchKernelGGL((dynscf_kernel<false, true, false>), dim3(gridM), dim3(block), 0, stream,
                           gs_xyz, gs_rot, node_xyz, node_quat, (const float*)nullptr,
                           node_sigma, node_sem,
                           attach_ind, ref_time, topo_knn, t_ptr, (const float4*)nullptr,
                           out, qb_ws, N, M);
        hipLaunchKernelGGL((k_elem<true>), dim3(gridN), dim3(block), 0, stream,
                           gs_scal, gs_opa, feat_dc, feat_rest, gs_rot, node_quat,
                           attach_ind, ref_time, qb_ws, out, N, M);
    } else {
        hipLaunchKernelGGL((dynscf_kernel<false, false, false>), dim3(gridM), dim3(block), 0, stream,
                           gs_xyz, gs_rot, node_xyz, node_quat, (const float*)nullptr,
                           node_sigma, node_sem,
                           attach_ind, ref_time, topo_knn, t_ptr, (const float4*)nullptr,
                           out, (float*)nullptr, N, M);
        hipLaunchKernelGGL((k_elem<false>), dim3(gridN), dim3(block), 0, stream,
                           gs_scal, gs_opa, feat_dc, feat_rest, gs_rot, node_quat,
                           attach_ind, ref_time, (const float*)nullptr, out, N, M);
    }
}

// Round 5
// 216.261 us; speedup vs baseline: 2.2070x; 1.1293x over previous
//
#include <hip/hip_runtime.h>

#define KNN 16
#define FSEM 32
#define LPG 4                 // 4 lanes cooperate per gaussian
#define NXCD 8
#define NSUB 256              // coarse sub-buckets per time slice

__device__ __forceinline__ float sigmoidf_(float x) { return 1.0f / (1.0f + __expf(-x)); }

// q / clip(|q|,1e-12) -> row-major 3x3
__device__ __forceinline__ void quat_to_R(float qw, float qx, float qy, float qz, float* R) {
    float d = qw * qw + qx * qx + qy * qy + qz * qz;
    float inv = rsqrtf(fmaxf(d, 1e-24f));
    float w = qw * inv, x = qx * inv, y = qy * inv, z = qz * inv;
    R[0] = 1.f - 2.f * (y * y + z * z); R[1] = 2.f * (x * y - w * z); R[2] = 2.f * (x * z + w * y);
    R[3] = 2.f * (x * y + w * z); R[4] = 1.f - 2.f * (x * x + z * z); R[5] = 2.f * (y * z - w * x);
    R[6] = 2.f * (x * z - w * y); R[7] = 2.f * (y * z + w * x); R[8] = 1.f - 2.f * (x * x + y * y);
}

// ---- fused prepack + histogram.
// pack:  packed[p] = {x,y,z,sigma, qw,qx,qy,qz} (32 B, line-friendly)
// hist:  coarse key = rt*NSUB + (a>>shift); rank[n] = arrival order in bucket.
// cnt must be zeroed (hipMemsetAsync) before this kernel. ----
__global__ void __launch_bounds__(256)
k_pack_hist(const float* __restrict__ node_xyz, const float* __restrict__ node_quat,
            const float* __restrict__ node_sigma,
            const int* __restrict__ attach, const int* __restrict__ rtime,
            float* __restrict__ packed, int* __restrict__ cnt, int* __restrict__ rank,
            int TM, int M, int N, int shift)
{
    int p = blockIdx.x * blockDim.x + threadIdx.x;
    if (p < TM) {
        const int node = p - (p / M) * M;          // p % M
        const float* x = node_xyz + 3 * (size_t)p;
        float4 a = make_float4(x[0], x[1], x[2], node_sigma[node]);
        float4 q = reinterpret_cast<const float4*>(node_quat)[p];
        float4* dst = reinterpret_cast<float4*>(packed + 8 * (size_t)p);
        dst[0] = a;
        dst[1] = q;
    }
    if (p < N && cnt) {
        const int key = rtime[p] * NSUB + (attach[p] >> shift);
        rank[p] = atomicAdd(&cnt[key], 1);
    }
}

// ---- two-level scan (R4's single-block scan over 10K buckets was ~40us of
// serial barriers on one CU; this is ~4us). ----
// level 1: exclusive scan within 256-bucket blocks, in-place; block totals out.
__global__ void __launch_bounds__(256)
k_scan1(int* __restrict__ cnt, int* __restrict__ blk, int B)
{
    __shared__ int sh[256];
    const int i = blockIdx.x * 256 + threadIdx.x;
    int v = (i < B) ? cnt[i] : 0;
    sh[threadIdx.x] = v;
    __syncthreads();
    int acc = v;
#pragma unroll
    for (int off = 1; off < 256; off <<= 1) {
        int u = (threadIdx.x >= off) ? sh[threadIdx.x - off] : 0;
        __syncthreads();
        acc += u;
        sh[threadIdx.x] = acc;
        __syncthreads();
    }
    if (i < B) cnt[i] = acc - v;                 // exclusive within block
    if (threadIdx.x == 255) blk[blockIdx.x] = acc;   // block total
}

// level 2: single-block exclusive scan of the (few dozen) block totals
__global__ void __launch_bounds__(256)
k_scan2(int* __restrict__ blk, int nblk)
{
    __shared__ int sh[256];
    __shared__ int carry_s;
    if (threadIdx.x == 0) carry_s = 0;
    __syncthreads();
    for (int base = 0; base < nblk; base += 256) {
        const int i = base + threadIdx.x;
        int v = (i < nblk) ? blk[i] : 0;
        sh[threadIdx.x] = v;
        __syncthreads();
        int acc = v;
#pragma unroll
        for (int off = 1; off < 256; off <<= 1) {
            int u = (threadIdx.x >= off) ? sh[threadIdx.x - off] : 0;
            __syncthreads();
            acc += u;
            sh[threadIdx.x] = acc;
            __syncthreads();
        }
        const int carry = carry_s;
        if (i < nblk) blk[i] = acc - v + carry;
        __syncthreads();
        if (threadIdx.x == 255) carry_s = carry + acc;
        __syncthreads();
    }
}

// ---- scatter + independent elementwise outputs (s, o, sph) fused.
// meta[2*pos]   = {n, a, rt, 0} (as float bits)
// meta[2*pos+1] = {gx, gy, gz, 0}
__global__ void __launch_bounds__(256)
k_scatter_elem(const int* __restrict__ attach, const int* __restrict__ rtime,
               const float* __restrict__ gs_xyz,
               const int* __restrict__ rank, const int* __restrict__ cnt,
               const int* __restrict__ blk,
               float4* __restrict__ meta,
               const float* __restrict__ gs_scal,
               const float* __restrict__ gs_opa,
               const float* __restrict__ feat_dc,
               const float* __restrict__ feat_rest,
               float* __restrict__ out,
               int N, int shift)
{
    int n = blockIdx.x * blockDim.x + threadIdx.x;
    if (n >= N) return;
    const int a = attach[n], rt = rtime[n];
    const int key = rt * NSUB + (a >> shift);
    const int pos = cnt[key] + blk[key >> 8] + rank[n];
    meta[2 * (size_t)pos]     = make_float4(__int_as_float(n), __int_as_float(a),
                                            __int_as_float(rt), 0.f);
    meta[2 * (size_t)pos + 1] = make_float4(gs_xyz[3 * (size_t)n + 0],
                                            gs_xyz[3 * (size_t)n + 1],
                                            gs_xyz[3 * (size_t)n + 2], 0.f);

    const size_t Ns = (size_t)N, ns = (size_t)n;
    float* os = out + 12 * Ns + 3 * ns;
    os[0] = 0.1f * sigmoidf_(gs_scal[3 * ns + 0]);
    os[1] = 0.1f * sigmoidf_(gs_scal[3 * ns + 1]);
    os[2] = 0.1f * sigmoidf_(gs_scal[3 * ns + 2]);

    out[15 * Ns + ns] = sigmoidf_(gs_opa[ns]);

    float* osph = out + 16 * Ns + 12 * ns;   // 16B-aligned
    float4 v0 = make_float4(feat_dc[3 * ns + 0], feat_dc[3 * ns + 1], feat_dc[3 * ns + 2],
                            feat_rest[9 * ns + 0]);
    float4 v1 = make_float4(feat_rest[9 * ns + 1], feat_rest[9 * ns + 2],
                            feat_rest[9 * ns + 3], feat_rest[9 * ns + 4]);
    float4 v2 = make_float4(feat_rest[9 * ns + 5], feat_rest[9 * ns + 6],
                            feat_rest[9 * ns + 7], feat_rest[9 * ns + 8]);
    reinterpret_cast<float4*>(osph)[0] = v0;
    reinterpret_cast<float4*>(osph)[1] = v1;
    reinterpret_cast<float4*>(osph)[2] = v2;
}

// ---- plain elementwise kernel (fallback paths only) ----
__global__ void __launch_bounds__(256)
k_elem(const float* __restrict__ gs_scal,
       const float* __restrict__ gs_opa,
       const float* __restrict__ feat_dc,
       const float* __restrict__ feat_rest,
       float* __restrict__ out, int N)
{
    const int n = blockIdx.x * blockDim.x + threadIdx.x;
    if (n >= N) return;
    const size_t Ns = (size_t)N, ns = (size_t)n;

    float* os = out + 12 * Ns + 3 * ns;
    os[0] = 0.1f * sigmoidf_(gs_scal[3 * ns + 0]);
    os[1] = 0.1f * sigmoidf_(gs_scal[3 * ns + 1]);
    os[2] = 0.1f * sigmoidf_(gs_scal[3 * ns + 2]);

    out[15 * Ns + ns] = sigmoidf_(gs_opa[ns]);

    float* osph = out + 16 * Ns + 12 * ns;
    float4 v0 = make_float4(feat_dc[3 * ns + 0], feat_dc[3 * ns + 1], feat_dc[3 * ns + 2],
                            feat_rest[9 * ns + 0]);
    float4 v1 = make_float4(feat_rest[9 * ns + 1], feat_rest[9 * ns + 2],
                            feat_rest[9 * ns + 3], feat_rest[9 * ns + 4]);
    float4 v2 = make_float4(feat_rest[9 * ns + 5], feat_rest[9 * ns + 6],
                            feat_rest[9 * ns + 7], feat_rest[9 * ns + 8]);
    reinterpret_cast<float4*>(osph)[0] = v0;
    reinterpret_cast<float4*>(osph)[1] = v1;
    reinterpret_cast<float4*>(osph)[2] = v2;
}

// ---- main skinning kernel: mu, fr (fused), sem ----
// Plain __launch_bounds__(256): R3 proved forcing 8 waves/SIMD clamps the
// allocator to 32 VGPR and spills the whole working set (WRITE_SIZE 40->511 MB,
// 67->306 us). fr fused back in: R0/R1 showed the FRSPLIT never saved VGPRs
// (84 fused vs 92 split) and the separate k_fr tail costs a dispatch + ~10 MB.
template<bool PACKED, bool SORTED>
__global__ void __launch_bounds__(256)
dynscf_kernel(const float* __restrict__ gs_xyz,
              const float* __restrict__ gs_rot,
              const float* __restrict__ node_xyz,
              const float* __restrict__ node_quat,
              const float* __restrict__ packed,
              const float* __restrict__ node_sigma,
              const float* __restrict__ node_sem,
              const int* __restrict__ attach_ind,
              const int* __restrict__ ref_time,
              const int* __restrict__ topo_knn,
              const int* __restrict__ t_ptr,
              const float4* __restrict__ meta,
              float* __restrict__ out,
              int N, int M)
{
    int bid = blockIdx.x;
    if (SORTED) {
        // m204 bijective chunked XCD swizzle: each XCD gets a contiguous
        // range of the rt-sorted gaussians -> its L2 holds few rt slices.
        const int nwg = gridDim.x;
        const int q = nwg / NXCD, r = nwg % NXCD;
        const int xcd = bid % NXCD, idx = bid / NXCD;
        bid = (xcd < r ? xcd * (q + 1) : r * (q + 1) + (xcd - r) * q) + idx;
    }
    const int tid = bid * blockDim.x + threadIdx.x;
    const int g   = tid >> 2;            // sorted-order group index
    const int sub = tid & (LPG - 1);
    if (g >= N) return;

    const int t = t_ptr[0];

    int n, a, rt;
    float gx, gy, gz;
    if (SORTED) {
        const float4 m0 = meta[2 * (size_t)g];
        const float4 m1 = meta[2 * (size_t)g + 1];
        n  = __float_as_int(m0.x);
        a  = __float_as_int(m0.y);
        rt = __float_as_int(m0.z);
        gx = m1.x; gy = m1.y; gz = m1.z;
    } else {
        n  = g;
        a  = attach_ind[n];
        rt = ref_time[n];
        gx = gs_xyz[3 * (size_t)n + 0];
        gy = gs_xyz[3 * (size_t)n + 1];
        gz = gs_xyz[3 * (size_t)n + 2];
    }

    const size_t base_rt = (size_t)rt * (size_t)M;
    const size_t base_t  = (size_t)t  * (size_t)M;

    // neighbor indices first so downstream gather addresses are known early
    const int4 kv = reinterpret_cast<const int4*>(topo_knn)[(size_t)a * (KNN / 4) + sub];
    const int js[4] = { kv.x, kv.y, kv.z, kv.w };

    // --- attach node @ ref time ---
    float apx, apy, apz, aqw, aqx, aqy, aqz;
    if (PACKED) {
        const float4* pk = reinterpret_cast<const float4*>(packed + (base_rt + (size_t)a) * 8);
        float4 xz = pk[0], qv = pk[1];
        apx = xz.x; apy = xz.y; apz = xz.z;
        aqw = qv.x; aqx = qv.y; aqy = qv.z; aqz = qv.w;
    } else {
        const float4 qv = *reinterpret_cast<const float4*>(node_quat + (base_rt + (size_t)a) * 4);
        const float* pa = node_xyz + (base_rt + (size_t)a) * 3;
        apx = pa[0]; apy = pa[1]; apz = pa[2];
        aqw = qv.x; aqx = qv.y; aqy = qv.z; aqz = qv.w;
    }
    float Rref[9];
    quat_to_R(aqw, aqx, aqy, aqz, Rref);

    const float xw0 = Rref[0] * gx + Rref[1] * gy + Rref[2] * gz + apx;
    const float xw1 = Rref[3] * gx + Rref[4] * gy + Rref[5] * gz + apy;
    const float xw2 = Rref[6] * gx + Rref[7] * gy + Rref[8] * gz + apz;

    float wsum = 0.f, mu0 = 0.f, mu1 = 0.f, mu2 = 0.f;
    float qb0 = 0.f, qb1 = 0.f, qb2 = 0.f, qb3 = 0.f;
    float wk[4];

#pragma unroll
    for (int k = 0; k < KNN / LPG; k++) {
        const int j = js[k];

        float prx, pry, prz, rw, rx, ry, rz;
        float plx, ply, plz, lw, lx, ly, lz;
        float sg;
        if (PACKED) {
            const float4* pkr = reinterpret_cast<const float4*>(packed + (base_rt + (size_t)j) * 8);
            float4 xr = pkr[0], qr = pkr[1];
            prx = xr.x; pry = xr.y; prz = xr.z; sg = xr.w;
            rw = qr.x; rx = qr.y; ry = qr.z; rz = qr.w;
            const float4* pkl = reinterpret_cast<const float4*>(packed + (base_t + (size_t)j) * 8);
            float4 xl = pkl[0], ql = pkl[1];
            plx = xl.x; ply = xl.y; plz = xl.z;
            lw = ql.x; lx = ql.y; ly = ql.z; lz = ql.w;
        } else {
            const float* pr = node_xyz + (base_rt + (size_t)j) * 3;
            prx = pr[0]; pry = pr[1]; prz = pr[2];
            const float4 qr = *reinterpret_cast<const float4*>(node_quat + (base_rt + (size_t)j) * 4);
            rw = qr.x; rx = qr.y; ry = qr.z; rz = qr.w;
            const float* pl = node_xyz + (base_t + (size_t)j) * 3;
            plx = pl[0]; ply = pl[1]; plz = pl[2];
            const float4 ql = *reinterpret_cast<const float4*>(node_quat + (base_t + (size_t)j) * 4);
            lw = ql.x; lx = ql.y; ly = ql.z; lz = ql.w;
            sg = node_sigma[j];
        }

        const float dx = xw0 - prx;
        const float dy = xw1 - pry;
        const float dz = xw2 - prz;
        const float dsq = dx * dx + dy * dy + dz * dz;

        const float w = __expf(-dsq / (2.f * sg * sg + 1e-8f));
        wk[k] = w;

        {
            float inv = rsqrtf(fmaxf(rw * rw + rx * rx + ry * ry + rz * rz, 1e-24f));
            rw *= inv; rx *= inv; ry *= inv; rz *= inv;
        }
        {
            float inv = rsqrtf(fmaxf(lw * lw + lx * lx + ly * ly + lz * lz, 1e-24f));
            lw *= inv; lx *= inv; ly *= inv; lz *= inv;
        }
        // q_rel = q_live * conj(q_ref)
        const float qw =  lw * rw + lx * rx + ly * ry + lz * rz;
        const float qx = -lw * rx + lx * rw - ly * rz + lz * ry;
        const float qy = -lw * ry + lx * rz + ly * rw - lz * rx;
        const float qz = -lw * rz - lx * ry + ly * rx + lz * rw;

        float Rr[9];
        quat_to_R(qw, qx, qy, qz, Rr);

        const float m0 = Rr[0] * dx + Rr[1] * dy + Rr[2] * dz + plx;
        const float m1 = Rr[3] * dx + Rr[4] * dy + Rr[5] * dz + ply;
        const float m2 = Rr[6] * dx + Rr[7] * dy + Rr[8] * dz + plz;

        wsum += w;
        mu0 += w * m0; mu1 += w * m1; mu2 += w * m2;
        qb0 += w * qw; qb1 += w * qx; qb2 += w * qy; qb3 += w * qz;
    }

    // group-reduce the 8 scalar accumulators (2 rounds within the 4-lane group)
#pragma unroll
    for (int m = 1; m < LPG; m <<= 1) {
        wsum += __shfl_xor(wsum, m);
        mu0  += __shfl_xor(mu0, m);  mu1 += __shfl_xor(mu1, m);  mu2 += __shfl_xor(mu2, m);
        qb0  += __shfl_xor(qb0, m);  qb1 += __shfl_xor(qb1, m);
        qb2  += __shfl_xor(qb2, m);  qb3 += __shfl_xor(qb3, m);
    }

    const float invw = 1.f / (wsum + 1e-8f);
    const size_t Ns = (size_t)N, ns = (size_t)n;

    // --- sem: feature-sliced. Lane `sub` owns features [8*sub, 8*sub+8) and
    // walks all 16 neighbors, pulling (j, w) from the owning lane via shfl. ---
    float sm0 = 0.f, sm1 = 0.f, sm2 = 0.f, sm3 = 0.f;
    float sm4 = 0.f, sm5 = 0.f, sm6 = 0.f, sm7 = 0.f;
    const float4* sem4 = reinterpret_cast<const float4*>(node_sem);
#pragma unroll
    for (int kk = 0; kk < KNN; kk++) {
        const int src = kk >> 2;        // lane within group that owns this neighbor
        const int idx = kk & 3;         // compile-time (loop fully unrolled)
        const int   jk = __shfl(js[idx], src, LPG);
        const float wkk = __shfl(wk[idx], src, LPG);
        const float4 v0 = sem4[(size_t)jk * (FSEM / 4) + sub * 2 + 0];
        const float4 v1 = sem4[(size_t)jk * (FSEM / 4) + sub * 2 + 1];
        sm0 += wkk * v0.x; sm1 += wkk * v0.y; sm2 += wkk * v0.z; sm3 += wkk * v0.w;
        sm4 += wkk * v1.x; sm5 += wkk * v1.y; sm6 += wkk * v1.z; sm7 += wkk * v1.w;
    }

    if (sub == 0) {
        out[3 * ns + 0] = mu0 * invw;
        out[3 * ns + 1] = mu1 * invw;
        out[3 * ns + 2] = mu2 * invw;
    } else if (sub == 1) {
        // fr_live = q2R(qb*invw) @ (Rref @ q2R(gs_rot)); invw BEFORE q2R (fp32
        // subnormal guard — r5 bug).
        const float4 qg = *reinterpret_cast<const float4*>(gs_rot + 4 * ns);
        float Rg[9];
        quat_to_R(qg.x, qg.y, qg.z, qg.w, Rg);
        float Rw[9];
#pragma unroll
        for (int i = 0; i < 3; i++)
#pragma unroll
            for (int j = 0; j < 3; j++)
                Rw[3 * i + j] = Rref[3 * i] * Rg[j] + Rref[3 * i + 1] * Rg[3 + j] + Rref[3 * i + 2] * Rg[6 + j];
        float Rb[9];
        quat_to_R(qb0 * invw, qb1 * invw, qb2 * invw, qb3 * invw, Rb);
        float* ofr = out + 3 * Ns + 9 * ns;
#pragma unroll
        for (int i = 0; i < 3; i++)
#pragma unroll
            for (int j = 0; j < 3; j++)
                ofr[3 * i + j] = Rb[3 * i] * Rw[j] + Rb[3 * i + 1] * Rw[3 + j] + Rb[3 * i + 2] * Rw[6 + j];
    }

    // sem_live: [28N, 60N); lane writes its own 2 float4s (one 128 B line/gaussian)
    float4* osem = reinterpret_cast<float4*>(out + 28 * Ns + FSEM * ns);
    osem[sub * 2 + 0] = make_float4(sm0 * invw, sm1 * invw, sm2 * invw, sm3 * invw);
    osem[sub * 2 + 1] = make_float4(sm4 * invw, sm5 * invw, sm6 * invw, sm7 * invw);
}

extern "C" void kernel_launch(void* const* d_in, const int* in_sizes, int n_in,
                              void* d_out, int out_size, void* d_ws, size_t ws_size,
                              hipStream_t stream)
{
    const float* gs_xyz     = (const float*)d_in[0];
    const float* gs_rot     = (const float*)d_in[1];
    const float* gs_scal    = (const float*)d_in[2];
    const float* gs_opa     = (const float*)d_in[3];
    const float* feat_dc    = (const float*)d_in[4];
    const float* feat_rest  = (const float*)d_in[5];
    const float* node_xyz   = (const float*)d_in[6];
    const float* node_quat  = (const float*)d_in[7];
    const float* node_sigma = (const float*)d_in[8];
    const float* node_sem   = (const float*)d_in[9];
    const int* attach_ind   = (const int*)d_in[10];
    const int* ref_time     = (const int*)d_in[11];
    const int* topo_knn     = (const int*)d_in[12];
    const int* t_ptr        = (const int*)d_in[13];

    const int N = in_sizes[0] / 3;
    const int M = in_sizes[8];                 // node_sigma is (M,1)
    const int TM = in_sizes[6] / 3;            // T*M
    const int T  = TM / M;
    const int B  = T * NSUB;                   // coarse buckets: rt x (a>>shift)

    int shift = 0;
    while (((M - 1) >> shift) >= NSUB) shift++;

    float* out = (float*)d_out;

    const int block = 256;
    const int gridN = (N + block - 1) / block;
    const long long threads = (long long)N * LPG;
    const int gridM = (int)((threads + block - 1) / block);
    const int gridPH = (((TM > N ? TM : N)) + block - 1) / block;
    const int nblkS = (B + 255) / 256;

    // workspace layout (floats/ints): packed | meta(2*float4/gauss) | cnt | blk | rank
    const size_t f_packed = (size_t)TM * 8;
    const size_t f_meta   = (size_t)N * 8;
    const size_t i_cnt    = (size_t)B;
    const size_t i_blk    = (size_t)nblkS;
    const size_t i_rank   = (size_t)N;
    const size_t need_sort   = (f_packed + f_meta + i_cnt + i_blk + i_rank) * sizeof(float);
    const size_t need_packed = f_packed * sizeof(float);

    if (ws_size >= need_sort) {
        float*  packed = (float*)d_ws;
        float4* meta   = (float4*)(packed + f_packed);
        int*    cnt    = (int*)(packed + f_packed + f_meta);
        int*    blk    = cnt + i_cnt;
        int*    rank   = blk + i_blk;

        hipMemsetAsync(cnt, 0, (size_t)B * sizeof(int), stream);
        hipLaunchKernelGGL(k_pack_hist, dim3(gridPH), dim3(block), 0, stream,
                           node_xyz, node_quat, node_sigma, attach_ind, ref_time,
                           packed, cnt, rank, TM, M, N, shift);
        hipLaunchKernelGGL(k_scan1, dim3(nblkS), dim3(block), 0, stream, cnt, blk, B);
        hipLaunchKernelGGL(k_scan2, dim3(1), dim3(block), 0, stream, blk, nblkS);
        hipLaunchKernelGGL(k_scatter_elem, dim3(gridN), dim3(block), 0, stream,
                           attach_ind, ref_time, gs_xyz, rank, cnt, blk, meta,
                           gs_scal, gs_opa, feat_dc, feat_rest, out, N, shift);
        hipLaunchKernelGGL((dynscf_kernel<true, true>), dim3(gridM), dim3(block), 0, stream,
                           gs_xyz, gs_rot, node_xyz, node_quat, packed, node_sigma, node_sem,
                           attach_ind, ref_time, topo_knn, t_ptr, meta, out, N, M);
    } else if (ws_size >= need_packed) {
        float* packed = (float*)d_ws;
        hipLaunchKernelGGL(k_pack_hist, dim3(gridPH), dim3(block), 0, stream,
                           node_xyz, node_quat, node_sigma, attach_ind, ref_time,
                           packed, (int*)nullptr, (int*)nullptr, TM, M, 0, shift);
        hipLaunchKernelGGL((dynscf_kernel<true, false>), dim3(gridM), dim3(block), 0, stream,
                           gs_xyz, gs_rot, node_xyz, node_quat, packed, node_sigma, node_sem,
                           attach_ind, ref_time, topo_knn, t_ptr, (const float4*)nullptr,
                           out, N, M);
        hipLaunchKernelGGL(k_elem, dim3(gridN), dim3(block), 0, stream,
                           gs_scal, gs_opa, feat_dc, feat_rest, out, N);
    } else {
        hipLaunchKernelGGL((dynscf_kernel<false, false>), dim3(gridM), dim3(block), 0, stream,
                           gs_xyz, gs_rot, node_xyz, node_quat, (const float*)nullptr,
                           node_sigma, node_sem,
                           attach_ind, ref_time, topo_knn, t_ptr, (const float4*)nullptr,
                           out, N, M);
        hipLaunchKernelGGL(k_elem, dim3(gridN), dim3(block), 0, stream,
                           gs_scal, gs_opa, feat_dc, feat_rest, out, N);
    }
}

// Round 6
// 212.176 us; speedup vs baseline: 2.2495x; 1.0193x over previous
//
#include <hip/hip_runtime.h>

#define KNN 16
#define FSEM 32
#define LPG 4                 // 4 lanes cooperate per gaussian
#define NXCD 8
#define CSTRIDE 32            // counter stride in ints (128 B) -> no line contention
#define MAXT 256              // max time steps supported by sorted path

__device__ __forceinline__ float sigmoidf_(float x) { return 1.0f / (1.0f + __expf(-x)); }

// q / clip(|q|,1e-12) -> row-major 3x3
__device__ __forceinline__ void quat_to_R(float qw, float qx, float qy, float qz, float* R) {
    float d = qw * qw + qx * qx + qy * qy + qz * qz;
    float inv = rsqrtf(fmaxf(d, 1e-24f));
    float w = qw * inv, x = qx * inv, y = qy * inv, z = qz * inv;
    R[0] = 1.f - 2.f * (y * y + z * z); R[1] = 2.f * (x * y - w * z); R[2] = 2.f * (x * z + w * y);
    R[3] = 2.f * (x * y + w * z); R[4] = 1.f - 2.f * (x * x + z * z); R[5] = 2.f * (y * z - w * x);
    R[6] = 2.f * (x * z - w * y); R[7] = 2.f * (y * z + w * x); R[8] = 1.f - 2.f * (x * x + y * y);
}

// ---- fused prepack + rt-histogram (LDS-aggregated; no rank array).
// pack: packed[p] = {x,y,z,sigma, qw,qx,qy,qz} (32 B, line-friendly)
// hist: cnt[rt*CSTRIDE] += block-local count. cnt pre-zeroed via memset. ----
__global__ void __launch_bounds__(256)
k_pack_hist(const float* __restrict__ node_xyz, const float* __restrict__ node_quat,
            const float* __restrict__ node_sigma,
            const int* __restrict__ rtime,
            float* __restrict__ packed, int* __restrict__ cnt,
            int TM, int M, int N, int T)
{
    __shared__ int lh[MAXT];
    if (threadIdx.x < MAXT) lh[threadIdx.x] = 0;
    __syncthreads();

    const int p = blockIdx.x * blockDim.x + threadIdx.x;
    if (cnt && p < N) atomicAdd(&lh[rtime[p]], 1);

    if (p < TM) {
        const int node = p - (p / M) * M;          // p % M
        const float* x = node_xyz + 3 * (size_t)p;
        float4 a = make_float4(x[0], x[1], x[2], node_sigma[node]);
        float4 q = reinterpret_cast<const float4*>(node_quat)[p];
        float4* dst = reinterpret_cast<float4*>(packed + 8 * (size_t)p);
        dst[0] = a;
        dst[1] = q;
    }

    __syncthreads();
    if (cnt && threadIdx.x < T) {
        const int c = lh[threadIdx.x];
        if (c > 0) atomicAdd(&cnt[threadIdx.x * CSTRIDE], c);
    }
}

// ---- scatter (computes its own prefix over T<=256 buckets) + elementwise
// outputs (s, o, sph) fused. No separate scan dispatches.
// meta[3*pos]   = {n, ~, rt, a} (as float bits)
// meta[3*pos+1] = {gx, gy, gz, 0}
// meta[3*pos+2] = gs_rot[n]   (sequential read here -> coalesced read in main)
__global__ void __launch_bounds__(256)
k_scatter_elem(const int* __restrict__ attach, const int* __restrict__ rtime,
               const float* __restrict__ gs_xyz,
               const float* __restrict__ gs_rot,
               const int* __restrict__ cnt, int* __restrict__ cur,
               float4* __restrict__ meta,
               const float* __restrict__ gs_scal,
               const float* __restrict__ gs_opa,
               const float* __restrict__ feat_dc,
               const float* __restrict__ feat_rest,
               float* __restrict__ out,
               int N, int T)
{
    __shared__ int lh[MAXT];     // block-local bucket counts -> local ranks
    __shared__ int bb[MAXT];     // this block's base within bucket (global cursor)
    __shared__ int pref[MAXT];   // exclusive prefix of global bucket counts

    if (threadIdx.x < MAXT) lh[threadIdx.x] = 0;
    __syncthreads();

    const int n = blockIdx.x * blockDim.x + threadIdx.x;
    const bool valid = (n < N);
    int a = 0, rt = 0, lrank = 0;
    if (valid) {
        a  = attach[n];
        rt = rtime[n];
        lrank = atomicAdd(&lh[rt], 1);
    }
    __syncthreads();

    if (threadIdx.x < T) {
        const int c = lh[threadIdx.x];
        bb[threadIdx.x] = (c > 0) ? atomicAdd(&cur[threadIdx.x * CSTRIDE], c) : 0;
        pref[threadIdx.x] = cnt[threadIdx.x * CSTRIDE];
    }
    __syncthreads();
    if (threadIdx.x == 0) {
        int run = 0;
#pragma unroll 4
        for (int i = 0; i < T; i++) { const int c = pref[i]; pref[i] = run; run += c; }
    }
    __syncthreads();

    if (!valid) return;

    const int pos = pref[rt] + bb[rt] + lrank;
    meta[3 * (size_t)pos]     = make_float4(__int_as_float(n), 0.f,
                                            __int_as_float(rt), __int_as_float(a));
    meta[3 * (size_t)pos + 1] = make_float4(gs_xyz[3 * (size_t)n + 0],
                                            gs_xyz[3 * (size_t)n + 1],
                                            gs_xyz[3 * (size_t)n + 2], 0.f);
    meta[3 * (size_t)pos + 2] = reinterpret_cast<const float4*>(gs_rot)[n];

    const size_t Ns = (size_t)N, ns = (size_t)n;
    float* os = out + 12 * Ns + 3 * ns;
    os[0] = 0.1f * sigmoidf_(gs_scal[3 * ns + 0]);
    os[1] = 0.1f * sigmoidf_(gs_scal[3 * ns + 1]);
    os[2] = 0.1f * sigmoidf_(gs_scal[3 * ns + 2]);

    out[15 * Ns + ns] = sigmoidf_(gs_opa[ns]);

    float* osph = out + 16 * Ns + 12 * ns;   // 16B-aligned
    float4 v0 = make_float4(feat_dc[3 * ns + 0], feat_dc[3 * ns + 1], feat_dc[3 * ns + 2],
                            feat_rest[9 * ns + 0]);
    float4 v1 = make_float4(feat_rest[9 * ns + 1], feat_rest[9 * ns + 2],
                            feat_rest[9 * ns + 3], feat_rest[9 * ns + 4]);
    float4 v2 = make_float4(feat_rest[9 * ns + 5], feat_rest[9 * ns + 6],
                            feat_rest[9 * ns + 7], feat_rest[9 * ns + 8]);
    reinterpret_cast<float4*>(osph)[0] = v0;
    reinterpret_cast<float4*>(osph)[1] = v1;
    reinterpret_cast<float4*>(osph)[2] = v2;
}

// ---- plain elementwise kernel (fallback paths only) ----
__global__ void __launch_bounds__(256)
k_elem(const float* __restrict__ gs_scal,
       const float* __restrict__ gs_opa,
       const float* __restrict__ feat_dc,
       const float* __restrict__ feat_rest,
       float* __restrict__ out, int N)
{
    const int n = blockIdx.x * blockDim.x + threadIdx.x;
    if (n >= N) return;
    const size_t Ns = (size_t)N, ns = (size_t)n;

    float* os = out + 12 * Ns + 3 * ns;
    os[0] = 0.1f * sigmoidf_(gs_scal[3 * ns + 0]);
    os[1] = 0.1f * sigmoidf_(gs_scal[3 * ns + 1]);
    os[2] = 0.1f * sigmoidf_(gs_scal[3 * ns + 2]);

    out[15 * Ns + ns] = sigmoidf_(gs_opa[ns]);

    float* osph = out + 16 * Ns + 12 * ns;
    float4 v0 = make_float4(feat_dc[3 * ns + 0], feat_dc[3 * ns + 1], feat_dc[3 * ns + 2],
                            feat_rest[9 * ns + 0]);
    float4 v1 = make_float4(feat_rest[9 * ns + 1], feat_rest[9 * ns + 2],
                            feat_rest[9 * ns + 3], feat_rest[9 * ns + 4]);
    float4 v2 = make_float4(feat_rest[9 * ns + 5], feat_rest[9 * ns + 6],
                            feat_rest[9 * ns + 7], feat_rest[9 * ns + 8]);
    reinterpret_cast<float4*>(osph)[0] = v0;
    reinterpret_cast<float4*>(osph)[1] = v1;
    reinterpret_cast<float4*>(osph)[2] = v2;
}

// ---- main skinning kernel: mu, fr (fused), sem ----
// Plain __launch_bounds__(256): R3 proved forcing waves/EU clamps the allocator
// unpredictably (asked 8 -> got 32 VGPR, full spill). Register trim instead:
// keep the attach QUATERNION (4 regs) live across the loops and recompute Rref
// in the fr branch (R5 kept the 9-reg matrix live -> 108 VGPR).
template<bool PACKED, bool SORTED>
__global__ void __launch_bounds__(256)
dynscf_kernel(const float* __restrict__ gs_xyz,
              const float* __restrict__ gs_rot,
              const float* __restrict__ node_xyz,
              const float* __restrict__ node_quat,
              const float* __restrict__ packed,
              const float* __restrict__ node_sigma,
              const float* __restrict__ node_sem,
              const int* __restrict__ attach_ind,
              const int* __restrict__ ref_time,
              const int* __restrict__ topo_knn,
              const int* __restrict__ t_ptr,
              const float4* __restrict__ meta,
              float* __restrict__ out,
              int N, int M)
{
    int bid = blockIdx.x;
    if (SORTED) {
        // m204 bijective chunked XCD swizzle: each XCD gets a contiguous
        // range of the rt-sorted gaussians -> its L2 holds few rt slices.
        const int nwg = gridDim.x;
        const int q = nwg / NXCD, r = nwg % NXCD;
        const int xcd = bid % NXCD, idx = bid / NXCD;
        bid = (xcd < r ? xcd * (q + 1) : r * (q + 1) + (xcd - r) * q) + idx;
    }
    const int tid = bid * blockDim.x + threadIdx.x;
    const int g   = tid >> 2;            // sorted-order group index
    const int sub = tid & (LPG - 1);
    if (g >= N) return;

    const int t = t_ptr[0];

    int n, a, rt;
    float gx, gy, gz;
    if (SORTED) {
        const float4 m0 = meta[3 * (size_t)g];
        const float4 m1 = meta[3 * (size_t)g + 1];
        n  = __float_as_int(m0.x);
        rt = __float_as_int(m0.z);
        a  = __float_as_int(m0.w);
        gx = m1.x; gy = m1.y; gz = m1.z;
    } else {
        n  = g;
        a  = attach_ind[n];
        rt = ref_time[n];
        gx = gs_xyz[3 * (size_t)n + 0];
        gy = gs_xyz[3 * (size_t)n + 1];
        gz = gs_xyz[3 * (size_t)n + 2];
    }

    const size_t base_rt = (size_t)rt * (size_t)M;
    const size_t base_t  = (size_t)t  * (size_t)M;

    // neighbor indices first so downstream gather addresses are known early
    const int4 kv = reinterpret_cast<const int4*>(topo_knn)[(size_t)a * (KNN / 4) + sub];
    const int js[4] = { kv.x, kv.y, kv.z, kv.w };

    // --- attach node @ ref time (keep quat live; Rref scoped, dies after xw) ---
    float apx, apy, apz, aqw, aqx, aqy, aqz;
    if (PACKED) {
        const float4* pk = reinterpret_cast<const float4*>(packed + (base_rt + (size_t)a) * 8);
        float4 xz = pk[0], qv = pk[1];
        apx = xz.x; apy = xz.y; apz = xz.z;
        aqw = qv.x; aqx = qv.y; aqy = qv.z; aqz = qv.w;
    } else {
        const float4 qv = *reinterpret_cast<const float4*>(node_quat + (base_rt + (size_t)a) * 4);
        const float* pa = node_xyz + (base_rt + (size_t)a) * 3;
        apx = pa[0]; apy = pa[1]; apz = pa[2];
        aqw = qv.x; aqx = qv.y; aqy = qv.z; aqz = qv.w;
    }
    float xw0, xw1, xw2;
    {
        float Rf[9];
        quat_to_R(aqw, aqx, aqy, aqz, Rf);
        xw0 = Rf[0] * gx + Rf[1] * gy + Rf[2] * gz + apx;
        xw1 = Rf[3] * gx + Rf[4] * gy + Rf[5] * gz + apy;
        xw2 = Rf[6] * gx + Rf[7] * gy + Rf[8] * gz + apz;
    }

    float wsum = 0.f, mu0 = 0.f, mu1 = 0.f, mu2 = 0.f;
    float qb0 = 0.f, qb1 = 0.f, qb2 = 0.f, qb3 = 0.f;
    float wk[4];

#pragma unroll
    for (int k = 0; k < KNN / LPG; k++) {
        const int j = js[k];

        float prx, pry, prz, rw, rx, ry, rz;
        float plx, ply, plz, lw, lx, ly, lz;
        float sg;
        if (PACKED) {
            const float4* pkr = reinterpret_cast<const float4*>(packed + (base_rt + (size_t)j) * 8);
            float4 xr = pkr[0], qr = pkr[1];
            prx = xr.x; pry = xr.y; prz = xr.z; sg = xr.w;
            rw = qr.x; rx = qr.y; ry = qr.z; rz = qr.w;
            const float4* pkl = reinterpret_cast<const float4*>(packed + (base_t + (size_t)j) * 8);
            float4 xl = pkl[0], ql = pkl[1];
            plx = xl.x; ply = xl.y; plz = xl.z;
            lw = ql.x; lx = ql.y; ly = ql.z; lz = ql.w;
        } else {
            const float* pr = node_xyz + (base_rt + (size_t)j) * 3;
            prx = pr[0]; pry = pr[1]; prz = pr[2];
            const float4 qr = *reinterpret_cast<const float4*>(node_quat + (base_rt + (size_t)j) * 4);
            rw = qr.x; rx = qr.y; ry = qr.z; rz = qr.w;
            const float* pl = node_xyz + (base_t + (size_t)j) * 3;
            plx = pl[0]; ply = pl[1]; plz = pl[2];
            const float4 ql = *reinterpret_cast<const float4*>(node_quat + (base_t + (size_t)j) * 4);
            lw = ql.x; lx = ql.y; ly = ql.z; lz = ql.w;
            sg = node_sigma[j];
        }

        const float dx = xw0 - prx;
        const float dy = xw1 - pry;
        const float dz = xw2 - prz;
        const float dsq = dx * dx + dy * dy + dz * dz;

        const float w = __expf(-dsq / (2.f * sg * sg + 1e-8f));
        wk[k] = w;

        {
            float inv = rsqrtf(fmaxf(rw * rw + rx * rx + ry * ry + rz * rz, 1e-24f));
            rw *= inv; rx *= inv; ry *= inv; rz *= inv;
        }
        {
            float inv = rsqrtf(fmaxf(lw * lw + lx * lx + ly * ly + lz * lz, 1e-24f));
            lw *= inv; lx *= inv; ly *= inv; lz *= inv;
        }
        // q_rel = q_live * conj(q_ref)
        const float qw =  lw * rw + lx * rx + ly * ry + lz * rz;
        const float qx = -lw * rx + lx * rw - ly * rz + lz * ry;
        const float qy = -lw * ry + lx * rz + ly * rw - lz * rx;
        const float qz = -lw * rz - lx * ry + ly * rx + lz * rw;

        float Rr[9];
        quat_to_R(qw, qx, qy, qz, Rr);

        const float m0 = Rr[0] * dx + Rr[1] * dy + Rr[2] * dz + plx;
        const float m1 = Rr[3] * dx + Rr[4] * dy + Rr[5] * dz + ply;
        const float m2 = Rr[6] * dx + Rr[7] * dy + Rr[8] * dz + plz;

        wsum += w;
        mu0 += w * m0; mu1 += w * m1; mu2 += w * m2;
        qb0 += w * qw; qb1 += w * qx; qb2 += w * qy; qb3 += w * qz;
    }

    // group-reduce the 8 scalar accumulators (2 rounds within the 4-lane group)
#pragma unroll
    for (int m = 1; m < LPG; m <<= 1) {
        wsum += __shfl_xor(wsum, m);
        mu0  += __shfl_xor(mu0, m);  mu1 += __shfl_xor(mu1, m);  mu2 += __shfl_xor(mu2, m);
        qb0  += __shfl_xor(qb0, m);  qb1 += __shfl_xor(qb1, m);
        qb2  += __shfl_xor(qb2, m);  qb3 += __shfl_xor(qb3, m);
    }

    const float invw = 1.f / (wsum + 1e-8f);
    const size_t Ns = (size_t)N, ns = (size_t)n;

    // --- sem: feature-sliced. Lane `sub` owns features [8*sub, 8*sub+8) and
    // walks all 16 neighbors, pulling (j, w) from the owning lane via shfl. ---
    float sm0 = 0.f, sm1 = 0.f, sm2 = 0.f, sm3 = 0.f;
    float sm4 = 0.f, sm5 = 0.f, sm6 = 0.f, sm7 = 0.f;
    const float4* sem4 = reinterpret_cast<const float4*>(node_sem);
#pragma unroll
    for (int kk = 0; kk < KNN; kk++) {
        const int src = kk >> 2;        // lane within group that owns this neighbor
        const int idx = kk & 3;         // compile-time (loop fully unrolled)
        const int   jk = __shfl(js[idx], src, LPG);
        const float wkk = __shfl(wk[idx], src, LPG);
        const float4 v0 = sem4[(size_t)jk * (FSEM / 4) + sub * 2 + 0];
        const float4 v1 = sem4[(size_t)jk * (FSEM / 4) + sub * 2 + 1];
        sm0 += wkk * v0.x; sm1 += wkk * v0.y; sm2 += wkk * v0.z; sm3 += wkk * v0.w;
        sm4 += wkk * v1.x; sm5 += wkk * v1.y; sm6 += wkk * v1.z; sm7 += wkk * v1.w;
    }

    if (sub == 0) {
        out[3 * ns + 0] = mu0 * invw;
        out[3 * ns + 1] = mu1 * invw;
        out[3 * ns + 2] = mu2 * invw;
    } else if (sub == 1) {
        // fr_live = q2R(qb*invw) @ (Rref @ q2R(gs_rot)); invw BEFORE q2R (fp32
        // subnormal guard — r5 bug). Rref recomputed here from the live quat.
        float4 qg;
        if (SORTED) qg = meta[3 * (size_t)g + 2];
        else        qg = *reinterpret_cast<const float4*>(gs_rot + 4 * ns);
        float Rref[9];
        quat_to_R(aqw, aqx, aqy, aqz, Rref);
        float Rg[9];
        quat_to_R(qg.x, qg.y, qg.z, qg.w, Rg);
        float Rw[9];
#pragma unroll
        for (int i = 0; i < 3; i++)
#pragma unroll
            for (int j = 0; j < 3; j++)
                Rw[3 * i + j] = Rref[3 * i] * Rg[j] + Rref[3 * i + 1] * Rg[3 + j] + Rref[3 * i + 2] * Rg[6 + j];
        float Rb[9];
        quat_to_R(qb0 * invw, qb1 * invw, qb2 * invw, qb3 * invw, Rb);
        float* ofr = out + 3 * Ns + 9 * ns;
#pragma unroll
        for (int i = 0; i < 3; i++)
#pragma unroll
            for (int j = 0; j < 3; j++)
                ofr[3 * i + j] = Rb[3 * i] * Rw[j] + Rb[3 * i + 1] * Rw[3 + j] + Rb[3 * i + 2] * Rw[6 + j];
    }

    // sem_live: [28N, 60N); lane writes its own 2 float4s (one 128 B line/gaussian)
    float4* osem = reinterpret_cast<float4*>(out + 28 * Ns + FSEM * ns);
    osem[sub * 2 + 0] = make_float4(sm0 * invw, sm1 * invw, sm2 * invw, sm3 * invw);
    osem[sub * 2 + 1] = make_float4(sm4 * invw, sm5 * invw, sm6 * invw, sm7 * invw);
}

extern "C" void kernel_launch(void* const* d_in, const int* in_sizes, int n_in,
                              void* d_out, int out_size, void* d_ws, size_t ws_size,
                              hipStream_t stream)
{
    const float* gs_xyz     = (const float*)d_in[0];
    const float* gs_rot     = (const float*)d_in[1];
    const float* gs_scal    = (const float*)d_in[2];
    const float* gs_opa     = (const float*)d_in[3];
    const float* feat_dc    = (const float*)d_in[4];
    const float* feat_rest  = (const float*)d_in[5];
    const float* node_xyz   = (const float*)d_in[6];
    const float* node_quat  = (const float*)d_in[7];
    const float* node_sigma = (const float*)d_in[8];
    const float* node_sem   = (const float*)d_in[9];
    const int* attach_ind   = (const int*)d_in[10];
    const int* ref_time     = (const int*)d_in[11];
    const int* topo_knn     = (const int*)d_in[12];
    const int* t_ptr        = (const int*)d_in[13];

    const int N = in_sizes[0] / 3;
    const int M = in_sizes[8];                 // node_sigma is (M,1)
    const int TM = in_sizes[6] / 3;            // T*M
    const int T  = TM / M;                     // rt-only sort: T buckets

    float* out = (float*)d_out;

    const int block = 256;
    const int gridN = (N + block - 1) / block;
    const long long threads = (long long)N * LPG;
    const int gridM = (int)((threads + block - 1) / block);
    const int gridPH = (((TM > N ? TM : N)) + block - 1) / block;

    // workspace layout (floats/ints): packed | meta(3*float4/gauss) | cnt | cur
    const size_t f_packed = (size_t)TM * 8;
    const size_t f_meta   = (size_t)N * 12;
    const size_t i_cnt    = (size_t)MAXT * CSTRIDE;   // strided counters
    const size_t i_cur    = (size_t)MAXT * CSTRIDE;
    const size_t need_sort   = (f_packed + f_meta + i_cnt + i_cur) * sizeof(float);
    const size_t need_packed = f_packed * sizeof(float);

    if (ws_size >= need_sort && T <= MAXT) {
        float*  packed = (float*)d_ws;
        float4* meta   = (float4*)(packed + f_packed);
        int*    cnt    = (int*)(packed + f_packed + f_meta);
        int*    cur    = cnt + i_cnt;

        // zero cnt+cur in one contiguous memset (graph-capture-safe, R5-proven)
        hipMemsetAsync(cnt, 0, (i_cnt + i_cur) * sizeof(int), stream);
        hipLaunchKernelGGL(k_pack_hist, dim3(gridPH), dim3(block), 0, stream,
                           node_xyz, node_quat, node_sigma, ref_time,
                           packed, cnt, TM, M, N, T);
        hipLaunchKernelGGL(k_scatter_elem, dim3(gridN), dim3(block), 0, stream,
                           attach_ind, ref_time, gs_xyz, gs_rot, cnt, cur, meta,
                           gs_scal, gs_opa, feat_dc, feat_rest, out, N, T);
        hipLaunchKernelGGL((dynscf_kernel<true, true>), dim3(gridM), dim3(block), 0, stream,
                           gs_xyz, gs_rot, node_xyz, node_quat, packed, node_sigma, node_sem,
                           attach_ind, ref_time, topo_knn, t_ptr, meta, out, N, M);
    } else if (ws_size >= need_packed) {
        float* packed = (float*)d_ws;
        hipLaunchKernelGGL(k_pack_hist, dim3(gridPH), dim3(block), 0, stream,
                           node_xyz, node_quat, node_sigma, ref_time,
                           packed, (int*)nullptr, TM, M, 0, T);
        hipLaunchKernelGGL((dynscf_kernel<true, false>), dim3(gridM), dim3(block), 0, stream,
                           gs_xyz, gs_rot, node_xyz, node_quat, packed, node_sigma, node_sem,
                           attach_ind, ref_time, topo_knn, t_ptr, (const float4*)nullptr,
                           out, N, M);
        hipLaunchKernelGGL(k_elem, dim3(gridN), dim3(block), 0, stream,
                           gs_scal, gs_opa, feat_dc, feat_rest, out, N);
    } else {
        hipLaunchKernelGGL((dynscf_kernel<false, false>), dim3(gridM), dim3(block), 0, stream,
                           gs_xyz, gs_rot, node_xyz, node_quat, (const float*)nullptr,
                           node_sigma, node_sem,
                           attach_ind, ref_time, topo_knn, t_ptr, (const float4*)nullptr,
                           out, N, M);
        hipLaunchKernelGGL(k_elem, dim3(gridN), dim3(block), 0, stream,
                           gs_scal, gs_opa, feat_dc, feat_rest, out, N);
    }
}